// Round 6
// baseline (345.613 us; speedup 1.0000x reference)
//
#include <hip/hip_runtime.h>

typedef short bf16x8 __attribute__((ext_vector_type(8)));
typedef float f32x4 __attribute__((ext_vector_type(4)));

#define NEG 0.01f

// wbf slab byte offsets (bf16, content pre-swizzled within rows: byte ^= (row&KEY)<<4, 16B granule)
#define OFF_P0  0        // [128][32]  rowB=64,  key (r&3)<<4 (pw0, k padded 16->32 with zeros)
#define OFF_P1  8192     // [128][128] rowB=256, key (r&7)<<4
#define OFF_M0  40960    // [128][128] x3 (mw0,mw1,mw2)
#define OFF_Q0A 139264   // [128][128] qw0 cols 0..127   (z3 part)
#define OFF_Q0B 172032   // [128][128] qw0 cols 128..255 (h part)
#define OFF_Q1  204800   // [64][128]
#define WBF_BYTES 221184

#define VMCNT0 asm volatile("s_waitcnt vmcnt(0)" ::: "memory")

__device__ __forceinline__ unsigned short f2bf(float f) {
  union { float f; unsigned u; } v; v.f = f;
  unsigned u = v.u;
  return (unsigned short)((u + 0x7fffu + ((u >> 16) & 1u)) >> 16);
}
__device__ __forceinline__ unsigned pack2(float a, float b) {
  return ((unsigned)f2bf(b) << 16) | (unsigned)f2bf(a);
}
__device__ __forceinline__ float bflo(unsigned u) { return __uint_as_float(u << 16); }
__device__ __forceinline__ float bfhi(unsigned u) { return __uint_as_float(u & 0xffff0000u); }
__device__ __forceinline__ float lrelu(float v) { return fmaxf(v, 0.0f) + NEG * fminf(v, 0.0f); }
__device__ __forceinline__ float tanh_fast(float x) {
  float e = __expf(2.0f * x);
  return 1.0f - __fdividef(2.0f, e + 1.0f);
}

// async global->LDS, 16B per lane (LDS dest = wave-uniform base + lane*16)
__device__ __forceinline__ void gll16(const void* g, void* l) {
  __builtin_amdgcn_global_load_lds((const __attribute__((address_space(1))) void*)g,
                                   (__attribute__((address_space(3))) void*)l, 16, 0, 0);
}

// stage 32 rows (256B each, swizzled content) from global into wave-private scr (linear)
__device__ __forceinline__ void gll_rows(const char* gsrc, char* scr, int strip, int N, int lane) {
  #pragma unroll
  for (int c = 0; c < 8; ++c) {
    int L = c * 1024 + lane * 16;
    int row = strip + (L >> 8);
    row = row < N ? row : N - 1;
    gll16(gsrc + (size_t)row * 256 + (L & 255), scr + c * 1024 + lane * 16);
  }
}

// linear copy wave scr (32 rows) -> global rows strip.. (predicated, full 64B sectors)
__device__ __forceinline__ void copy_rows_out(const char* scr, char* gdst, int strip, int N, int lane) {
  #pragma unroll
  for (int c = 0; c < 8; ++c) {
    int L = c * 1024 + lane * 16;
    int row = strip + (L >> 8);
    if (row < N) *(uint4*)(gdst + (size_t)strip * 256 + L) = *(const uint4*)(scr + L);
  }
}

__device__ __forceinline__ void zacc82(f32x4 acc[8][2]) {
  #pragma unroll
  for (int m = 0; m < 8; ++m)
    #pragma unroll
    for (int n = 0; n < 2; ++n) { f32x4 z = {0.f,0.f,0.f,0.f}; acc[m][n] = z; }
}

// K=128 GEMM vs [128][128] swizzled slab (wbase may be global wbf or LDS); D[ch][node], 32 nodes/wave
__device__ __forceinline__ void gemm128(const char* wbase, const bf16x8 b[2][4],
                                        f32x4 acc[8][2], int l15, int lg) {
  #pragma unroll
  for (int ks = 0; ks < 4; ++ks)
    #pragma unroll
    for (int mf = 0; mf < 8; ++mf) {
      const int row = 16*mf + l15;
      bf16x8 a = *(const bf16x8*)(wbase + row*256 + ((16*lg + 64*ks) ^ ((row&7)<<4)));
      acc[mf][0] = __builtin_amdgcn_mfma_f32_16x16x32_bf16(a, b[0][ks], acc[mf][0], 0,0,0);
      acc[mf][1] = __builtin_amdgcn_mfma_f32_16x16x32_bf16(a, b[1][ks], acc[mf][1], 0,0,0);
    }
}

// read B-frags (activations) from wave-private swizzled scr
__device__ __forceinline__ void read_bfrags(const char* scr, bf16x8 b[2][4], int l15, int lg) {
  #pragma unroll
  for (int nf = 0; nf < 2; ++nf) {
    const int n = 16*nf + l15;
    #pragma unroll
    for (int ks = 0; ks < 4; ++ks)
      b[nf][ks] = *(const bf16x8*)(scr + n*256 + ((16*lg + 64*ks) ^ ((n&7)<<4)));
  }
}

// bias + act -> wave-private scr (swizzled b64 writes)
template<int ACT>  // 0 lrelu, 1 tanh
__device__ __forceinline__ void ep_lds(const f32x4 acc[8][2], const float* __restrict__ bias,
                                       char* scr, int l15, int lg) {
  #pragma unroll
  for (int mf = 0; mf < 8; ++mf) {
    const int ch4 = 16*mf + 4*lg;
    const float4 bv = *(const float4*)(bias + ch4);
    #pragma unroll
    for (int nf = 0; nf < 2; ++nf) {
      const int n = 16*nf + l15;
      float v0 = acc[mf][nf][0]+bv.x, v1 = acc[mf][nf][1]+bv.y;
      float v2 = acc[mf][nf][2]+bv.z, v3 = acc[mf][nf][3]+bv.w;
      if (ACT == 0) { v0=lrelu(v0); v1=lrelu(v1); v2=lrelu(v2); v3=lrelu(v3); }
      else { v0=tanh_fast(v0); v1=tanh_fast(v1); v2=tanh_fast(v2); v3=tanh_fast(v3); }
      uint2 o = { pack2(v0,v1), pack2(v2,v3) };
      *(uint2*)(scr + n*256 + ((32*mf + 8*lg) ^ ((n&7)<<4))) = o;
    }
  }
}

// ---------------- weight pack (f32 -> bf16, pre-swizzled slabs) + deg zero ----------------
extern "C" __global__ void __launch_bounds__(256) wpack_kernel(
    const float* __restrict__ pw0, const float* __restrict__ pw1,
    const float* __restrict__ mw0, const float* __restrict__ mw1, const float* __restrict__ mw2,
    const float* __restrict__ qw0, const float* __restrict__ qw1,
    char* wbf, int* deg, int N) {
  int gid = blockIdx.x * 256 + threadIdx.x;
  if (gid < 13824) {
    int c = gid;
    const float* src = nullptr;
    int dstB = 0;
    bool zero = false;
    if (c < 512) { int r = c >> 2, q = c & 3;
      dstB = OFF_P0 + r*64 + ((q*16) ^ ((r&3)<<4));
      if (q < 2) src = pw0 + r*16 + q*8; else zero = true;
    } else if (c < 2560) { int i = c - 512, r = i >> 4, q = i & 15;
      dstB = OFF_P1 + r*256 + ((q*16) ^ ((r&7)<<4));
      src = pw1 + r*128 + q*8;
    } else if (c < 8704) { int i = c - 2560, sl = i >> 11, j = i & 2047, r = j >> 4, q = j & 15;
      const float* m = (sl==0) ? mw0 : ((sl==1) ? mw1 : mw2);
      dstB = OFF_M0 + sl*32768 + r*256 + ((q*16) ^ ((r&7)<<4));
      src = m + r*128 + q*8;
    } else if (c < 10752) { int i = c - 8704, r = i >> 4, q = i & 15;
      dstB = OFF_Q0A + r*256 + ((q*16) ^ ((r&7)<<4));
      src = qw0 + r*256 + q*8;
    } else if (c < 12800) { int i = c - 10752, r = i >> 4, q = i & 15;
      dstB = OFF_Q0B + r*256 + ((q*16) ^ ((r&7)<<4));
      src = qw0 + r*256 + 128 + q*8;
    } else { int i = c - 12800, r = i >> 4, q = i & 15;
      dstB = OFF_Q1 + r*256 + ((q*16) ^ ((r&7)<<4));
      src = qw1 + r*128 + q*8;
    }
    ushort4 lo, hi;
    if (zero) { lo.x=lo.y=lo.z=lo.w=0; hi.x=hi.y=hi.z=hi.w=0; }
    else {
      float4 a = *(const float4*)src, b = *(const float4*)(src + 4);
      lo.x=f2bf(a.x); lo.y=f2bf(a.y); lo.z=f2bf(a.z); lo.w=f2bf(a.w);
      hi.x=f2bf(b.x); hi.y=f2bf(b.y); hi.z=f2bf(b.z); hi.w=f2bf(b.w);
    }
    *(ushort4*)(wbf + dstB) = lo;
    *(ushort4*)(wbf + dstB + 8) = hi;
  }
  if (gid < N) deg[gid] = 0;
}

// ---------------- prep: x[N,16] -> h (swizzled-content bf16 rows); fused dst histogram ----------------
// weights read from L2-resident wbf (no LDS weight staging); 64KB LDS -> 2 blocks/CU
extern "C" __global__ void __launch_bounds__(512, 2) prep_kernel(
    const float* __restrict__ x,
    const float* __restrict__ pb0, const float* __restrict__ pb1,
    const char* __restrict__ wbf,
    const int* __restrict__ ei, int* deg, int E,
    char* hB, int N) {
  __shared__ char scr_all[8 * 8192];
  const int tid = threadIdx.x, lane = tid & 63, wv = tid >> 6;
  const int l15 = lane & 15, lg = lane >> 4;
  char* scr = scr_all + wv * 8192;

  // fused histogram of dst (deg zeroed by wpack_kernel)
  for (int e = blockIdx.x*512 + tid; e < E; e += gridDim.x*512)
    atomicAdd(&deg[ei[E + e]], 1);

  const int strip = blockIdx.x*256 + wv*32;
  if (strip >= N) return;

  // layer 0: K=32 (k>=16 zero), B-frags direct from x
  bf16x8 bx[2];
  #pragma unroll
  for (int nf = 0; nf < 2; ++nf) {
    int node = strip + 16*nf + l15; node = node < N ? node : N-1;
    if (lg < 2) {
      float4 u = *(const float4*)(x + (size_t)node*16 + lg*8);
      float4 v = *(const float4*)(x + (size_t)node*16 + lg*8 + 4);
      bf16x8 t;
      t[0]=(short)f2bf(u.x); t[1]=(short)f2bf(u.y); t[2]=(short)f2bf(u.z); t[3]=(short)f2bf(u.w);
      t[4]=(short)f2bf(v.x); t[5]=(short)f2bf(v.y); t[6]=(short)f2bf(v.z); t[7]=(short)f2bf(v.w);
      bx[nf] = t;
    } else {
      bf16x8 t = {0,0,0,0,0,0,0,0}; bx[nf] = t;
    }
  }
  f32x4 acc[8][2];
  zacc82(acc);
  #pragma unroll
  for (int mf = 0; mf < 8; ++mf) {
    const int row = 16*mf + l15;
    bf16x8 a = *(const bf16x8*)(wbf + OFF_P0 + row*64 + ((16*lg) ^ ((row&3)<<4)));
    acc[mf][0] = __builtin_amdgcn_mfma_f32_16x16x32_bf16(a, bx[0], acc[mf][0], 0,0,0);
    acc[mf][1] = __builtin_amdgcn_mfma_f32_16x16x32_bf16(a, bx[1], acc[mf][1], 0,0,0);
  }
  ep_lds<0>(acc, pb0, scr, l15, lg);
  // layer 1: K=128, tanh -> h
  bf16x8 b1[2][4];
  read_bfrags(scr, b1, l15, lg);
  zacc82(acc);
  gemm128(wbf + OFF_P1, b1, acc, l15, lg);
  ep_lds<1>(acc, pb1, scr, l15, lg);
  copy_rows_out(scr, hB, strip, N, lane);
}

// ---------------- fused CSR scan: deg -> offs/cur (single block, N <= 131072) ----------------
extern "C" __global__ void __launch_bounds__(1024) csr_kernel(
    const int* __restrict__ deg, int* offs, int* cur, int N) {
  __shared__ int sums[1024];
  const int t = threadIdx.x;
  const int i0 = t * 128;
  int s = 0;
  if (i0 < N) {
    int lim = (i0 + 128 < N) ? i0 + 128 : N;
    int i = i0;
    for (; i + 4 <= lim; i += 4) { int4 d = *(const int4*)(deg + i); s += d.x + d.y + d.z + d.w; }
    for (; i < lim; ++i) s += deg[i];
  }
  sums[t] = s;
  __syncthreads();
  for (int off = 1; off < 1024; off <<= 1) {
    int v = sums[t];
    int u = (t >= off) ? sums[t - off] : 0;
    __syncthreads();
    sums[t] = v + u;
    __syncthreads();
  }
  int run = (t == 0) ? 0 : sums[t - 1];
  if (i0 < N) {
    int lim = (i0 + 128 < N) ? i0 + 128 : N;
    int i = i0;
    for (; i + 4 <= lim; i += 4) {
      int4 d = *(const int4*)(deg + i);
      int4 o; o.x = run; o.y = run + d.x; o.z = o.y + d.y; o.w = o.z + d.z;
      *(int4*)(offs + i) = o; *(int4*)(cur + i) = o;
      run = o.w + d.w;
    }
    for (; i < lim; ++i) { offs[i] = run; cur[i] = run; run += deg[i]; }
  }
}

extern "C" __global__ void __launch_bounds__(256) scatter_kernel(
    const int* __restrict__ ei, const float* __restrict__ ew,
    int* cur, int2* recs, int E) {
  int e = blockIdx.x * 256 + threadIdx.x;
  if (e < E) {
    int dst = ei[E + e];
    int slot = atomicAdd(&cur[dst], 1);
    int2 r; r.x = ei[e]; r.y = __float_as_int(ew[e]);
    recs[slot] = r;
  }
}

// ---------------- aggregation: z = h_dst + sum relu(h_src + w*elw + elb) ----------------
extern "C" __global__ void __launch_bounds__(256) agg_kernel(
    const int* __restrict__ offs, const int* __restrict__ cur,
    const int2* __restrict__ recs,
    const float* __restrict__ elw, const float* __restrict__ elb,
    const char* __restrict__ hB, char* zB, int N) {
  const int lane = threadIdx.x & 63, wv = threadIdx.x >> 6;
  const int node = blockIdx.x * 4 + wv;
  if (node >= N) return;
  const float2 wl = *(const float2*)(elw + 2*lane);
  const float2 bl = *(const float2*)(elb + 2*lane);
  const int byteL = lane * 4;
  const int s = offs[node], e = cur[node];
  float c0 = 0.f, c1 = 0.f;
  int j = s;
  for (; j + 4 <= e; j += 4) {
    int2 r0 = recs[j], r1 = recs[j+1], r2 = recs[j+2], r3 = recs[j+3];
    unsigned u0 = *(const unsigned*)(hB + (size_t)r0.x*256 + (byteL ^ ((r0.x&7)<<4)));
    unsigned u1 = *(const unsigned*)(hB + (size_t)r1.x*256 + (byteL ^ ((r1.x&7)<<4)));
    unsigned u2 = *(const unsigned*)(hB + (size_t)r2.x*256 + (byteL ^ ((r2.x&7)<<4)));
    unsigned u3 = *(const unsigned*)(hB + (size_t)r3.x*256 + (byteL ^ ((r3.x&7)<<4)));
    float w0 = __int_as_float(r0.y), w1 = __int_as_float(r1.y);
    float w2 = __int_as_float(r2.y), w3 = __int_as_float(r3.y);
    c0 += fmaxf(bflo(u0) + w0*wl.x + bl.x, 0.f); c1 += fmaxf(bfhi(u0) + w0*wl.y + bl.y, 0.f);
    c0 += fmaxf(bflo(u1) + w1*wl.x + bl.x, 0.f); c1 += fmaxf(bfhi(u1) + w1*wl.y + bl.y, 0.f);
    c0 += fmaxf(bflo(u2) + w2*wl.x + bl.x, 0.f); c1 += fmaxf(bfhi(u2) + w2*wl.y + bl.y, 0.f);
    c0 += fmaxf(bflo(u3) + w3*wl.x + bl.x, 0.f); c1 += fmaxf(bfhi(u3) + w3*wl.y + bl.y, 0.f);
  }
  for (; j < e; ++j) {
    int2 r = recs[j];
    unsigned u = *(const unsigned*)(hB + (size_t)r.x*256 + (byteL ^ ((r.x&7)<<4)));
    float w = __int_as_float(r.y);
    c0 += fmaxf(bflo(u) + w*wl.x + bl.x, 0.f);
    c1 += fmaxf(bfhi(u) + w*wl.y + bl.y, 0.f);
  }
  unsigned hs = *(const unsigned*)(hB + (size_t)node*256 + (byteL ^ ((node&7)<<4)));
  unsigned o = pack2(bflo(hs) + c0, bfhi(hs) + c1);
  *(unsigned*)(zB + (size_t)node*256 + (byteL ^ ((node&7)<<4))) = o;
}

// ---------------- fused node MLP + post: z -> z3 -> [z3|h] -> out ----------------
// all weights read from L2-resident wbf; LDS = per-wave scratch only (64KB -> 2 blocks/CU)
extern "C" __global__ void __launch_bounds__(512, 2) node_kernel(
    const char* __restrict__ zB, const char* hB, const char* __restrict__ wbf,
    const float* __restrict__ mb0, const float* __restrict__ mb1, const float* __restrict__ mb2,
    const float* __restrict__ qb0, const float* __restrict__ qb1,
    float* out, int N) {
  __shared__ char scr_all[8 * 8192];
  const int tid = threadIdx.x, lane = tid & 63, wv = tid >> 6;
  const int l15 = lane & 15, lg = lane >> 4;
  char* scr = scr_all + wv * 8192;

  const int strip = blockIdx.x*256 + wv*32;
  if (strip >= N) return;

  gll_rows(zB, scr, strip, N, lane);
  VMCNT0;

  bf16x8 b0[2][4];
  read_bfrags(scr, b0, l15, lg);
  f32x4 acc[8][2];
  zacc82(acc);
  gemm128(wbf + OFF_M0, b0, acc, l15, lg);
  ep_lds<0>(acc, mb0, scr, l15, lg);

  bf16x8 b1[2][4];
  read_bfrags(scr, b1, l15, lg);
  zacc82(acc);
  gemm128(wbf + OFF_M0 + 32768, b1, acc, l15, lg);
  ep_lds<0>(acc, mb1, scr, l15, lg);

  bf16x8 b2[2][4];
  read_bfrags(scr, b2, l15, lg);
  zacc82(acc);
  gemm128(wbf + OFF_M0 + 65536, b2, acc, l15, lg);
  ep_lds<1>(acc, mb2, scr, l15, lg);   // z3 (tanh) in scr

  // post layer 0: qw0a @ z3 + qw0b @ h
  bf16x8 bz[2][4];
  read_bfrags(scr, bz, l15, lg);
  // h B-frags gathered directly from global (rows of this wave's strip; L2/L3-resident)
  bf16x8 bh[2][4];
  #pragma unroll
  for (int nf = 0; nf < 2; ++nf) {
    int node = strip + 16*nf + l15; node = node < N ? node : N-1;
    const char* hr = hB + (size_t)node*256;
    const int sw = (node&7) << 4;
    #pragma unroll
    for (int ks = 0; ks < 4; ++ks)
      bh[nf][ks] = *(const bf16x8*)(hr + ((16*lg + 64*ks) ^ sw));
  }
  zacc82(acc);
  gemm128(wbf + OFF_Q0A, bz, acc, l15, lg);
  gemm128(wbf + OFF_Q0B, bh, acc, l15, lg);
  ep_lds<0>(acc, qb0, scr, l15, lg);   // t

  // post layer 1: 64 channels, tanh -> out (float4 stores, full sectors)
  bf16x8 bt[2][4];
  read_bfrags(scr, bt, l15, lg);
  f32x4 a2[4][2];
  #pragma unroll
  for (int m = 0; m < 4; ++m)
    #pragma unroll
    for (int n = 0; n < 2; ++n) { f32x4 z = {0.f,0.f,0.f,0.f}; a2[m][n] = z; }
  #pragma unroll
  for (int ks = 0; ks < 4; ++ks)
    #pragma unroll
    for (int mf = 0; mf < 4; ++mf) {
      const int row = 16*mf + l15;
      bf16x8 a = *(const bf16x8*)(wbf + OFF_Q1 + row*256 + ((16*lg + 64*ks) ^ ((row&7)<<4)));
      a2[mf][0] = __builtin_amdgcn_mfma_f32_16x16x32_bf16(a, bt[0][ks], a2[mf][0], 0,0,0);
      a2[mf][1] = __builtin_amdgcn_mfma_f32_16x16x32_bf16(a, bt[1][ks], a2[mf][1], 0,0,0);
    }
  #pragma unroll
  for (int mf = 0; mf < 4; ++mf) {
    const int ch4 = 16*mf + 4*lg;
    const float4 bv = *(const float4*)(qb1 + ch4);
    #pragma unroll
    for (int nf = 0; nf < 2; ++nf) {
      const int node = strip + 16*nf + l15;
      if (node < N) {
        float4 o;
        o.x = tanh_fast(a2[mf][nf][0] + bv.x);
        o.y = tanh_fast(a2[mf][nf][1] + bv.y);
        o.z = tanh_fast(a2[mf][nf][2] + bv.z);
        o.w = tanh_fast(a2[mf][nf][3] + bv.w);
        *(float4*)(out + (size_t)node*64 + ch4) = o;
      }
    }
  }
}

extern "C" void kernel_launch(void* const* d_in, const int* in_sizes, int n_in,
                              void* d_out, int out_size, void* d_ws, size_t ws_size,
                              hipStream_t stream) {
  const float* x   = (const float*)d_in[0];
  const int*   ei  = (const int*)d_in[1];
  const float* ew  = (const float*)d_in[2];
  const float* pw0 = (const float*)d_in[3];
  const float* pb0 = (const float*)d_in[4];
  const float* pw1 = (const float*)d_in[5];
  const float* pb1 = (const float*)d_in[6];
  const float* elw = (const float*)d_in[7];
  const float* elb = (const float*)d_in[8];
  const float* mw0 = (const float*)d_in[9];
  const float* mb0 = (const float*)d_in[10];
  const float* mw1 = (const float*)d_in[11];
  const float* mb1 = (const float*)d_in[12];
  const float* mw2 = (const float*)d_in[13];
  const float* mb2 = (const float*)d_in[14];
  const float* qw0 = (const float*)d_in[15];
  const float* qb0 = (const float*)d_in[16];
  const float* qw1 = (const float*)d_in[17];
  const float* qb1 = (const float*)d_in[18];
  float* out = (float*)d_out;

  const int N = in_sizes[0] / 16;
  const int E = in_sizes[1] / 2;

  char* p = (char*)d_ws;
  auto alloc = [&](size_t bytes) { char* r = p; p += (bytes + 255) & ~(size_t)255; return r; };
  const size_t rowBytes = (size_t)N * 256;

  char* zB      = alloc(rowBytes);           // bf16 [N][128], swizzled content
  int2* recs    = (int2*)alloc((size_t)E * 8);
  int*  deg     = (int*)alloc((size_t)N * 4);
  int*  offs    = (int*)alloc((size_t)N * 4);
  int*  cur     = (int*)alloc((size_t)N * 4);
  char* wbf     = alloc(WBF_BYTES);

  char* hB;
  if ((size_t)(p - (char*)d_ws) + rowBytes <= ws_size) {
    hB = alloc(rowBytes);
  } else {
    // alias output: N*64 f32 == N*128 bf16; node_kernel reads its own strip's h rows
    // before writing the same rows of out
    hB = (char*)d_out;
  }

  const int nblk = (N + 255) / 256;
  const int eblk = (E + 255) / 256;
  const int pgrid = ((13824 > N ? 13824 : N) + 255) / 256;

  wpack_kernel<<<dim3(pgrid), dim3(256), 0, stream>>>(pw0, pw1, mw0, mw1, mw2, qw0, qw1,
                                                      wbf, deg, N);
  prep_kernel<<<dim3(nblk), dim3(512), 0, stream>>>(x, pb0, pb1, wbf, ei, deg, E, hB, N);
  csr_kernel<<<dim3(1), dim3(1024), 0, stream>>>(deg, offs, cur, N);
  scatter_kernel<<<dim3(eblk), dim3(256), 0, stream>>>(ei, ew, cur, recs, E);
  agg_kernel<<<dim3((N + 3) / 4), dim3(256), 0, stream>>>(offs, cur, recs, elw, elb, hB, zB, N);
  node_kernel<<<dim3(nblk), dim3(512), 0, stream>>>(zB, hB, wbf, mb0, mb1, mb2,
                                                    qb0, qb1, out, N);
}

// Round 7
// 312.050 us; speedup vs baseline: 1.1076x; 1.1076x over previous
//
#include <hip/hip_runtime.h>

typedef short bf16x8 __attribute__((ext_vector_type(8)));
typedef float f32x4 __attribute__((ext_vector_type(4)));

#define NEG 0.01f

// wbf slab byte offsets (bf16, content pre-swizzled within rows: byte ^= (row&KEY)<<4, 16B granule)
#define OFF_P0  0        // [128][32]  rowB=64,  key (r&3)<<4 (pw0, k padded 16->32 with zeros)
#define OFF_P1  8192     // [128][128] rowB=256, key (r&7)<<4
#define OFF_M0  40960    // [128][128] x3 (mw0,mw1,mw2)
#define OFF_Q0A 139264   // [128][128] qw0 cols 0..127   (z3 part)
#define OFF_Q0B 172032   // [128][128] qw0 cols 128..255 (h part)
#define OFF_Q1  204800   // [64][128]
#define WBF_BYTES 221184

#define VMCNT0 asm volatile("s_waitcnt vmcnt(0)" ::: "memory")

__device__ __forceinline__ unsigned short f2bf(float f) {
  union { float f; unsigned u; } v; v.f = f;
  unsigned u = v.u;
  return (unsigned short)((u + 0x7fffu + ((u >> 16) & 1u)) >> 16);
}
__device__ __forceinline__ unsigned pack2(float a, float b) {
  return ((unsigned)f2bf(b) << 16) | (unsigned)f2bf(a);
}
__device__ __forceinline__ float bflo(unsigned u) { return __uint_as_float(u << 16); }
__device__ __forceinline__ float bfhi(unsigned u) { return __uint_as_float(u & 0xffff0000u); }
__device__ __forceinline__ float lrelu(float v) { return fmaxf(v, 0.0f) + NEG * fminf(v, 0.0f); }
__device__ __forceinline__ float tanh_fast(float x) {
  float e = __expf(2.0f * x);
  return 1.0f - __fdividef(2.0f, e + 1.0f);
}

// async global->LDS, 16B per lane (LDS dest = wave-uniform base + lane*16)
__device__ __forceinline__ void gll16(const void* g, void* l) {
  __builtin_amdgcn_global_load_lds((const __attribute__((address_space(1))) void*)g,
                                   (__attribute__((address_space(3))) void*)l, 16, 0, 0);
}

// linear slab stage: nchunks 1KB chunks, wave j owns chunks j, j+nw, ...
__device__ __forceinline__ void gll_lin(const char* g, char* l, int nchunks, int wv, int nw, int lane) {
  for (int j = wv; j < nchunks; j += nw)
    gll16(g + j * 1024 + lane * 16, l + j * 1024 + lane * 16);
}

// stage 32 rows (256B each, swizzled content) from global into wave-private scr (linear)
__device__ __forceinline__ void gll_rows(const char* gsrc, char* scr, int strip, int N, int lane) {
  #pragma unroll
  for (int c = 0; c < 8; ++c) {
    int L = c * 1024 + lane * 16;
    int row = strip + (L >> 8);
    row = row < N ? row : N - 1;
    gll16(gsrc + (size_t)row * 256 + (L & 255), scr + c * 1024 + lane * 16);
  }
}

// linear copy wave scr (32 rows) -> global rows strip.. (predicated, full 64B sectors)
__device__ __forceinline__ void copy_rows_out(const char* scr, char* gdst, int strip, int N, int lane) {
  #pragma unroll
  for (int c = 0; c < 8; ++c) {
    int L = c * 1024 + lane * 16;
    int row = strip + (L >> 8);
    if (row < N) *(uint4*)(gdst + (size_t)strip * 256 + L) = *(const uint4*)(scr + L);
  }
}

__device__ __forceinline__ void zacc82(f32x4 acc[8][2]) {
  #pragma unroll
  for (int m = 0; m < 8; ++m)
    #pragma unroll
    for (int n = 0; n < 2; ++n) { f32x4 z = {0.f,0.f,0.f,0.f}; acc[m][n] = z; }
}

// K=128 GEMM vs [128][128] swizzled slab (LDS); D[ch][node], 32 nodes/wave
__device__ __forceinline__ void gemm128(const char* wbase, const bf16x8 b[2][4],
                                        f32x4 acc[8][2], int l15, int lg) {
  __builtin_amdgcn_s_setprio(1);
  #pragma unroll
  for (int ks = 0; ks < 4; ++ks)
    #pragma unroll
    for (int mf = 0; mf < 8; ++mf) {
      const int row = 16*mf + l15;
      bf16x8 a = *(const bf16x8*)(wbase + row*256 + ((16*lg + 64*ks) ^ ((row&7)<<4)));
      acc[mf][0] = __builtin_amdgcn_mfma_f32_16x16x32_bf16(a, b[0][ks], acc[mf][0], 0,0,0);
      acc[mf][1] = __builtin_amdgcn_mfma_f32_16x16x32_bf16(a, b[1][ks], acc[mf][1], 0,0,0);
    }
  __builtin_amdgcn_s_setprio(0);
}

// read B-frags (activations) from wave-private swizzled scr
__device__ __forceinline__ void read_bfrags(const char* scr, bf16x8 b[2][4], int l15, int lg) {
  #pragma unroll
  for (int nf = 0; nf < 2; ++nf) {
    const int n = 16*nf + l15;
    #pragma unroll
    for (int ks = 0; ks < 4; ++ks)
      b[nf][ks] = *(const bf16x8*)(scr + n*256 + ((16*lg + 64*ks) ^ ((n&7)<<4)));
  }
}

// bias + act -> wave-private scr (swizzled b64 writes)
template<int ACT>  // 0 lrelu, 1 tanh
__device__ __forceinline__ void ep_lds(const f32x4 acc[8][2], const float* __restrict__ bias,
                                       char* scr, int l15, int lg) {
  #pragma unroll
  for (int mf = 0; mf < 8; ++mf) {
    const int ch4 = 16*mf + 4*lg;
    const float4 bv = *(const float4*)(bias + ch4);
    #pragma unroll
    for (int nf = 0; nf < 2; ++nf) {
      const int n = 16*nf + l15;
      float v0 = acc[mf][nf][0]+bv.x, v1 = acc[mf][nf][1]+bv.y;
      float v2 = acc[mf][nf][2]+bv.z, v3 = acc[mf][nf][3]+bv.w;
      if (ACT == 0) { v0=lrelu(v0); v1=lrelu(v1); v2=lrelu(v2); v3=lrelu(v3); }
      else { v0=tanh_fast(v0); v1=tanh_fast(v1); v2=tanh_fast(v2); v3=tanh_fast(v3); }
      uint2 o = { pack2(v0,v1), pack2(v2,v3) };
      *(uint2*)(scr + n*256 + ((32*mf + 8*lg) ^ ((n&7)<<4))) = o;
    }
  }
}

// ---------------- weight pack (f32 -> bf16, pre-swizzled slabs) + deg zero ----------------
extern "C" __global__ void __launch_bounds__(256) wpack_kernel(
    const float* __restrict__ pw0, const float* __restrict__ pw1,
    const float* __restrict__ mw0, const float* __restrict__ mw1, const float* __restrict__ mw2,
    const float* __restrict__ qw0, const float* __restrict__ qw1,
    char* wbf, int* deg, int N) {
  int gid = blockIdx.x * 256 + threadIdx.x;
  if (gid < 13824) {
    int c = gid;
    const float* src = nullptr;
    int dstB = 0;
    bool zero = false;
    if (c < 512) { int r = c >> 2, q = c & 3;
      dstB = OFF_P0 + r*64 + ((q*16) ^ ((r&3)<<4));
      if (q < 2) src = pw0 + r*16 + q*8; else zero = true;
    } else if (c < 2560) { int i = c - 512, r = i >> 4, q = i & 15;
      dstB = OFF_P1 + r*256 + ((q*16) ^ ((r&7)<<4));
      src = pw1 + r*128 + q*8;
    } else if (c < 8704) { int i = c - 2560, sl = i >> 11, j = i & 2047, r = j >> 4, q = j & 15;
      const float* m = (sl==0) ? mw0 : ((sl==1) ? mw1 : mw2);
      dstB = OFF_M0 + sl*32768 + r*256 + ((q*16) ^ ((r&7)<<4));
      src = m + r*128 + q*8;
    } else if (c < 10752) { int i = c - 8704, r = i >> 4, q = i & 15;
      dstB = OFF_Q0A + r*256 + ((q*16) ^ ((r&7)<<4));
      src = qw0 + r*256 + q*8;
    } else if (c < 12800) { int i = c - 10752, r = i >> 4, q = i & 15;
      dstB = OFF_Q0B + r*256 + ((q*16) ^ ((r&7)<<4));
      src = qw0 + r*256 + 128 + q*8;
    } else { int i = c - 12800, r = i >> 4, q = i & 15;
      dstB = OFF_Q1 + r*256 + ((q*16) ^ ((r&7)<<4));
      src = qw1 + r*128 + q*8;
    }
    ushort4 lo, hi;
    if (zero) { lo.x=lo.y=lo.z=lo.w=0; hi.x=hi.y=hi.z=hi.w=0; }
    else {
      float4 a = *(const float4*)src, b = *(const float4*)(src + 4);
      lo.x=f2bf(a.x); lo.y=f2bf(a.y); lo.z=f2bf(a.z); lo.w=f2bf(a.w);
      hi.x=f2bf(b.x); hi.y=f2bf(b.y); hi.z=f2bf(b.z); hi.w=f2bf(b.w);
    }
    *(ushort4*)(wbf + dstB) = lo;
    *(ushort4*)(wbf + dstB + 8) = hi;
  }
  if (gid < N) deg[gid] = 0;
}

// ---------------- prep: x[N,16] -> h; fused dst histogram; P weights LDS-resident ----------------
extern "C" __global__ void __launch_bounds__(512) prep_kernel(
    const float* __restrict__ x,
    const float* __restrict__ pb0, const float* __restrict__ pb1,
    const char* __restrict__ wbf,
    const int* __restrict__ ei, int* deg, int E,
    char* hB, int N, int ntiles) {
  __shared__ char wP[40960];
  __shared__ char scr_all[8 * 8192];
  const int tid = threadIdx.x, lane = tid & 63, wv = tid >> 6;
  const int l15 = lane & 15, lg = lane >> 4;

  gll_lin(wbf + OFF_P0, wP, 40, wv, 8, lane);
  for (int e = blockIdx.x*512 + tid; e < E; e += gridDim.x*512)
    atomicAdd(&deg[ei[E + e]], 1);
  VMCNT0; __syncthreads();
  char* scr = scr_all + wv * 8192;

  for (int tile = blockIdx.x; tile < ntiles; tile += gridDim.x) {
    const int strip = tile*256 + wv*32;
    if (strip >= N) continue;
    // layer 0: K=32 (k>=16 zero), B-frags direct from x
    bf16x8 bx[2];
    #pragma unroll
    for (int nf = 0; nf < 2; ++nf) {
      int node = strip + 16*nf + l15; node = node < N ? node : N-1;
      if (lg < 2) {
        float4 u = *(const float4*)(x + (size_t)node*16 + lg*8);
        float4 v = *(const float4*)(x + (size_t)node*16 + lg*8 + 4);
        bf16x8 t;
        t[0]=(short)f2bf(u.x); t[1]=(short)f2bf(u.y); t[2]=(short)f2bf(u.z); t[3]=(short)f2bf(u.w);
        t[4]=(short)f2bf(v.x); t[5]=(short)f2bf(v.y); t[6]=(short)f2bf(v.z); t[7]=(short)f2bf(v.w);
        bx[nf] = t;
      } else {
        bf16x8 t = {0,0,0,0,0,0,0,0}; bx[nf] = t;
      }
    }
    f32x4 acc[8][2];
    zacc82(acc);
    __builtin_amdgcn_s_setprio(1);
    #pragma unroll
    for (int mf = 0; mf < 8; ++mf) {
      const int row = 16*mf + l15;
      bf16x8 a = *(const bf16x8*)(wP + row*64 + ((16*lg) ^ ((row&3)<<4)));
      acc[mf][0] = __builtin_amdgcn_mfma_f32_16x16x32_bf16(a, bx[0], acc[mf][0], 0,0,0);
      acc[mf][1] = __builtin_amdgcn_mfma_f32_16x16x32_bf16(a, bx[1], acc[mf][1], 0,0,0);
    }
    __builtin_amdgcn_s_setprio(0);
    ep_lds<0>(acc, pb0, scr, l15, lg);
    bf16x8 b1[2][4];
    read_bfrags(scr, b1, l15, lg);
    zacc82(acc);
    gemm128(wP + 8192, b1, acc, l15, lg);
    ep_lds<1>(acc, pb1, scr, l15, lg);
    copy_rows_out(scr, hB, strip, N, lane);
  }
}

// ---------------- fused CSR scan: deg -> offs/cur (single block, N <= 131072) ----------------
extern "C" __global__ void __launch_bounds__(1024) csr_kernel(
    const int* __restrict__ deg, int* offs, int* cur, int N) {
  __shared__ int sums[1024];
  const int t = threadIdx.x;
  const int i0 = t * 128;
  int s = 0;
  if (i0 < N) {
    int lim = (i0 + 128 < N) ? i0 + 128 : N;
    int i = i0;
    for (; i + 4 <= lim; i += 4) { int4 d = *(const int4*)(deg + i); s += d.x + d.y + d.z + d.w; }
    for (; i < lim; ++i) s += deg[i];
  }
  sums[t] = s;
  __syncthreads();
  for (int off = 1; off < 1024; off <<= 1) {
    int v = sums[t];
    int u = (t >= off) ? sums[t - off] : 0;
    __syncthreads();
    sums[t] = v + u;
    __syncthreads();
  }
  int run = (t == 0) ? 0 : sums[t - 1];
  if (i0 < N) {
    int lim = (i0 + 128 < N) ? i0 + 128 : N;
    int i = i0;
    for (; i + 4 <= lim; i += 4) {
      int4 d = *(const int4*)(deg + i);
      int4 o; o.x = run; o.y = run + d.x; o.z = o.y + d.y; o.w = o.z + d.z;
      *(int4*)(offs + i) = o; *(int4*)(cur + i) = o;
      run = o.w + d.w;
    }
    for (; i < lim; ++i) { offs[i] = run; cur[i] = run; run += deg[i]; }
  }
}

extern "C" __global__ void __launch_bounds__(256) scatter_kernel(
    const int* __restrict__ ei, const float* __restrict__ ew,
    int* cur, int2* recs, int E) {
  int e = blockIdx.x * 256 + threadIdx.x;
  if (e < E) {
    int dst = ei[E + e];
    int slot = atomicAdd(&cur[dst], 1);
    int2 r; r.x = ei[e]; r.y = __float_as_int(ew[e]);
    recs[slot] = r;
  }
}

// ---------------- aggregation: z = h_dst + sum relu(h_src + w*elw + elb) ----------------
extern "C" __global__ void __launch_bounds__(256) agg_kernel(
    const int* __restrict__ offs, const int* __restrict__ cur,
    const int2* __restrict__ recs,
    const float* __restrict__ elw, const float* __restrict__ elb,
    const char* __restrict__ hB, char* zB, int N) {
  const int lane = threadIdx.x & 63, wv = threadIdx.x >> 6;
  const int node = blockIdx.x * 4 + wv;
  if (node >= N) return;
  const float2 wl = *(const float2*)(elw + 2*lane);
  const float2 bl = *(const float2*)(elb + 2*lane);
  const int byteL = lane * 4;
  const int s = offs[node], e = cur[node];
  float c0 = 0.f, c1 = 0.f;
  int j = s;
  for (; j + 4 <= e; j += 4) {
    int2 r0 = recs[j], r1 = recs[j+1], r2 = recs[j+2], r3 = recs[j+3];
    unsigned u0 = *(const unsigned*)(hB + (size_t)r0.x*256 + (byteL ^ ((r0.x&7)<<4)));
    unsigned u1 = *(const unsigned*)(hB + (size_t)r1.x*256 + (byteL ^ ((r1.x&7)<<4)));
    unsigned u2 = *(const unsigned*)(hB + (size_t)r2.x*256 + (byteL ^ ((r2.x&7)<<4)));
    unsigned u3 = *(const unsigned*)(hB + (size_t)r3.x*256 + (byteL ^ ((r3.x&7)<<4)));
    float w0 = __int_as_float(r0.y), w1 = __int_as_float(r1.y);
    float w2 = __int_as_float(r2.y), w3 = __int_as_float(r3.y);
    c0 += fmaxf(bflo(u0) + w0*wl.x + bl.x, 0.f); c1 += fmaxf(bfhi(u0) + w0*wl.y + bl.y, 0.f);
    c0 += fmaxf(bflo(u1) + w1*wl.x + bl.x, 0.f); c1 += fmaxf(bfhi(u1) + w1*wl.y + bl.y, 0.f);
    c0 += fmaxf(bflo(u2) + w2*wl.x + bl.x, 0.f); c1 += fmaxf(bfhi(u2) + w2*wl.y + bl.y, 0.f);
    c0 += fmaxf(bflo(u3) + w3*wl.x + bl.x, 0.f); c1 += fmaxf(bfhi(u3) + w3*wl.y + bl.y, 0.f);
  }
  for (; j < e; ++j) {
    int2 r = recs[j];
    unsigned u = *(const unsigned*)(hB + (size_t)r.x*256 + (byteL ^ ((r.x&7)<<4)));
    float w = __int_as_float(r.y);
    c0 += fmaxf(bflo(u) + w*wl.x + bl.x, 0.f);
    c1 += fmaxf(bfhi(u) + w*wl.y + bl.y, 0.f);
  }
  unsigned hs = *(const unsigned*)(hB + (size_t)node*256 + (byteL ^ ((node&7)<<4)));
  unsigned o = pack2(bflo(hs) + c0, bfhi(hs) + c1);
  *(unsigned*)(zB + (size_t)node*256 + (byteL ^ ((node&7)<<4))) = o;
}

// ---------------- node MLP part A: z -> z3 (mw0,mw1,mw2 LDS-resident; persistent) ----------------
extern "C" __global__ void __launch_bounds__(448) nodeA_kernel(
    const char* __restrict__ zB, const char* __restrict__ wbf,
    const float* __restrict__ mb0, const float* __restrict__ mb1, const float* __restrict__ mb2,
    char* z3, int N, int ntiles) {
  __shared__ char wM[98304];
  __shared__ char scr_all[7 * 8192];
  const int tid = threadIdx.x, lane = tid & 63, wv = tid >> 6;
  const int l15 = lane & 15, lg = lane >> 4;

  gll_lin(wbf + OFF_M0, wM, 96, wv, 7, lane);
  VMCNT0; __syncthreads();
  char* scr = scr_all + wv * 8192;

  for (int tile = blockIdx.x; tile < ntiles; tile += gridDim.x) {
    const int strip = tile*224 + wv*32;
    if (strip >= N) continue;
    gll_rows(zB, scr, strip, N, lane);
    VMCNT0;
    bf16x8 b0[2][4];
    read_bfrags(scr, b0, l15, lg);
    f32x4 acc[8][2];
    zacc82(acc);
    gemm128(wM, b0, acc, l15, lg);
    ep_lds<0>(acc, mb0, scr, l15, lg);
    bf16x8 b1[2][4];
    read_bfrags(scr, b1, l15, lg);
    zacc82(acc);
    gemm128(wM + 32768, b1, acc, l15, lg);
    ep_lds<0>(acc, mb1, scr, l15, lg);
    bf16x8 b2[2][4];
    read_bfrags(scr, b2, l15, lg);
    zacc82(acc);
    gemm128(wM + 65536, b2, acc, l15, lg);
    ep_lds<1>(acc, mb2, scr, l15, lg);
    copy_rows_out(scr, z3, strip, N, lane);
  }
}

// ---------------- node MLP part B: [z3 | h] -> post -> out (Q slabs LDS-resident; persistent) ----------------
extern "C" __global__ void __launch_bounds__(512) nodeB_kernel(
    const char* __restrict__ z3, const char* hB, const char* __restrict__ wbf,
    const float* __restrict__ qb0, const float* __restrict__ qb1,
    float* out, int N, int ntiles) {
  __shared__ char wQ[81920];         // Q0a @0, Q0b @32768, Q1 @65536
  __shared__ char scr_all[8 * 8192];
  const int tid = threadIdx.x, lane = tid & 63, wv = tid >> 6;
  const int l15 = lane & 15, lg = lane >> 4;

  gll_lin(wbf + OFF_Q0A, wQ, 80, wv, 8, lane);
  VMCNT0; __syncthreads();
  char* scr = scr_all + wv * 8192;

  for (int tile = blockIdx.x; tile < ntiles; tile += gridDim.x) {
    const int strip = tile*256 + wv*32;
    if (strip >= N) continue;
    gll_rows(z3, scr, strip, N, lane);
    // h B-frags gathered directly from global while z3 stage is in flight
    bf16x8 bh[2][4];
    #pragma unroll
    for (int nf = 0; nf < 2; ++nf) {
      int node = strip + 16*nf + l15; node = node < N ? node : N-1;
      const char* hr = hB + (size_t)node*256;
      const int sw = (node&7) << 4;
      #pragma unroll
      for (int ks = 0; ks < 4; ++ks)
        bh[nf][ks] = *(const bf16x8*)(hr + ((16*lg + 64*ks) ^ sw));
    }
    VMCNT0;
    bf16x8 bz[2][4];
    read_bfrags(scr, bz, l15, lg);
    f32x4 acc[8][2];
    zacc82(acc);
    gemm128(wQ, bz, acc, l15, lg);          // qw0a @ z3
    gemm128(wQ + 32768, bh, acc, l15, lg);  // += qw0b @ h
    ep_lds<0>(acc, qb0, scr, l15, lg);      // lrelu -> t

    bf16x8 bt[2][4];
    read_bfrags(scr, bt, l15, lg);
    f32x4 a2[4][2];
    #pragma unroll
    for (int m = 0; m < 4; ++m)
      #pragma unroll
      for (int n = 0; n < 2; ++n) { f32x4 z = {0.f,0.f,0.f,0.f}; a2[m][n] = z; }
    __builtin_amdgcn_s_setprio(1);
    #pragma unroll
    for (int ks = 0; ks < 4; ++ks)
      #pragma unroll
      for (int mf = 0; mf < 4; ++mf) {
        const int row = 16*mf + l15;
        bf16x8 a = *(const bf16x8*)(wQ + 65536 + row*256 + ((16*lg + 64*ks) ^ ((row&7)<<4)));
        a2[mf][0] = __builtin_amdgcn_mfma_f32_16x16x32_bf16(a, bt[0][ks], a2[mf][0], 0,0,0);
        a2[mf][1] = __builtin_amdgcn_mfma_f32_16x16x32_bf16(a, bt[1][ks], a2[mf][1], 0,0,0);
      }
    __builtin_amdgcn_s_setprio(0);
    #pragma unroll
    for (int mf = 0; mf < 4; ++mf) {
      const int ch4 = 16*mf + 4*lg;
      const float4 bv = *(const float4*)(qb1 + ch4);
      #pragma unroll
      for (int nf = 0; nf < 2; ++nf) {
        const int node = strip + 16*nf + l15;
        if (node < N) {
          float4 o;
          o.x = tanh_fast(a2[mf][nf][0] + bv.x);
          o.y = tanh_fast(a2[mf][nf][1] + bv.y);
          o.z = tanh_fast(a2[mf][nf][2] + bv.z);
          o.w = tanh_fast(a2[mf][nf][3] + bv.w);
          *(float4*)(out + (size_t)node*64 + ch4) = o;
        }
      }
    }
  }
}

extern "C" void kernel_launch(void* const* d_in, const int* in_sizes, int n_in,
                              void* d_out, int out_size, void* d_ws, size_t ws_size,
                              hipStream_t stream) {
  const float* x   = (const float*)d_in[0];
  const int*   ei  = (const int*)d_in[1];
  const float* ew  = (const float*)d_in[2];
  const float* pw0 = (const float*)d_in[3];
  const float* pb0 = (const float*)d_in[4];
  const float* pw1 = (const float*)d_in[5];
  const float* pb1 = (const float*)d_in[6];
  const float* elw = (const float*)d_in[7];
  const float* elb = (const float*)d_in[8];
  const float* mw0 = (const float*)d_in[9];
  const float* mb0 = (const float*)d_in[10];
  const float* mw1 = (const float*)d_in[11];
  const float* mb1 = (const float*)d_in[12];
  const float* mw2 = (const float*)d_in[13];
  const float* mb2 = (const float*)d_in[14];
  const float* qw0 = (const float*)d_in[15];
  const float* qb0 = (const float*)d_in[16];
  const float* qw1 = (const float*)d_in[17];
  const float* qb1 = (const float*)d_in[18];
  float* out = (float*)d_out;

  const int N = in_sizes[0] / 16;
  const int E = in_sizes[1] / 2;

  char* p = (char*)d_ws;
  auto alloc = [&](size_t bytes) { char* r = p; p += (bytes + 255) & ~(size_t)255; return r; };
  const size_t rowBytes = (size_t)N * 256;

  char* zB      = alloc(rowBytes);           // bf16 [N][128], swizzled content
  char* z3      = alloc(rowBytes);           // bf16 [N][128], swizzled content
  int2* recs    = (int2*)alloc((size_t)E * 8);
  int*  deg     = (int*)alloc((size_t)N * 4);
  int*  offs    = (int*)alloc((size_t)N * 4);
  int*  cur     = (int*)alloc((size_t)N * 4);
  char* wbf     = alloc(WBF_BYTES);

  char* hB;
  if ((size_t)(p - (char*)d_ws) + rowBytes <= ws_size) {
    hB = alloc(rowBytes);
  } else {
    hB = (char*)d_out;  // alias: each node's h row read before that node's out write
  }

  const int ntilesP = (N + 255) / 256;
  const int ntilesA = (N + 223) / 224;
  const int ntilesB = (N + 255) / 256;
  const int eblk = (E + 255) / 256;
  const int pgrid = ((13824 > N ? 13824 : N) + 255) / 256;

  wpack_kernel<<<dim3(pgrid), dim3(256), 0, stream>>>(pw0, pw1, mw0, mw1, mw2, qw0, qw1,
                                                      wbf, deg, N);
  prep_kernel<<<dim3(256), dim3(512), 0, stream>>>(x, pb0, pb1, wbf, ei, deg, E, hB, N, ntilesP);
  csr_kernel<<<dim3(1), dim3(1024), 0, stream>>>(deg, offs, cur, N);
  scatter_kernel<<<dim3(eblk), dim3(256), 0, stream>>>(ei, ew, cur, recs, E);
  agg_kernel<<<dim3((N + 3) / 4), dim3(256), 0, stream>>>(offs, cur, recs, elw, elb, hB, zB, N);
  nodeA_kernel<<<dim3(256), dim3(448), 0, stream>>>(zB, wbf, mb0, mb1, mb2, z3, N, ntilesA);
  nodeB_kernel<<<dim3(256), dim3(512), 0, stream>>>(z3, hB, wbf, qb0, qb1, out, N, ntilesB);
}

// Round 8
// 259.298 us; speedup vs baseline: 1.3329x; 1.2034x over previous
//
#include <hip/hip_runtime.h>

typedef short bf16x8 __attribute__((ext_vector_type(8)));
typedef float f32x4 __attribute__((ext_vector_type(4)));

#define NEG 0.01f

// wbf slab byte offsets (bf16, content pre-swizzled within rows: byte ^= (row&KEY)<<4, 16B granule)
#define OFF_P0  0        // [128][32]  rowB=64,  key (r&3)<<4 (pw0, k padded 16->32 with zeros)
#define OFF_P1  8192     // [128][128] rowB=256, key (r&7)<<4
#define OFF_M0  40960    // [128][128] x3 (mw0,mw1,mw2)
#define OFF_Q0A 139264   // [128][128] qw0 cols 0..127   (z3 part)
#define OFF_Q0B 172032   // [128][128] qw0 cols 128..255 (h part)
#define OFF_Q1  204800   // [64][128]
#define WBF_BYTES 221184

#define VMCNT0 asm volatile("s_waitcnt vmcnt(0)" ::: "memory")

__device__ __forceinline__ unsigned short f2bf(float f) {
  union { float f; unsigned u; } v; v.f = f;
  unsigned u = v.u;
  return (unsigned short)((u + 0x7fffu + ((u >> 16) & 1u)) >> 16);
}
__device__ __forceinline__ unsigned pack2(float a, float b) {
  return ((unsigned)f2bf(b) << 16) | (unsigned)f2bf(a);
}
__device__ __forceinline__ float bflo(unsigned u) { return __uint_as_float(u << 16); }
__device__ __forceinline__ float bfhi(unsigned u) { return __uint_as_float(u & 0xffff0000u); }
__device__ __forceinline__ float lrelu(float v) { return fmaxf(v, 0.0f) + NEG * fminf(v, 0.0f); }
__device__ __forceinline__ float tanh_fast(float x) {
  float e = __expf(2.0f * x);
  return 1.0f - __fdividef(2.0f, e + 1.0f);
}

// async global->LDS, 16B per lane (LDS dest = wave-uniform base + lane*16)
__device__ __forceinline__ void gll16(const void* g, void* l) {
  __builtin_amdgcn_global_load_lds((const __attribute__((address_space(1))) void*)g,
                                   (__attribute__((address_space(3))) void*)l, 16, 0, 0);
}

// linear slab stage: nchunks 1KB chunks, wave j owns chunks j, j+nw, ...
__device__ __forceinline__ void gll_lin(const char* g, char* l, int nchunks, int wv, int nw, int lane) {
  for (int j = wv; j < nchunks; j += nw)
    gll16(g + j * 1024 + lane * 16, l + j * 1024 + lane * 16);
}

// stage 32 rows (256B each, swizzled content) from global into wave-private scr (linear)
__device__ __forceinline__ void gll_rows(const char* gsrc, char* scr, int strip, int N, int lane) {
  #pragma unroll
  for (int c = 0; c < 8; ++c) {
    int L = c * 1024 + lane * 16;
    int row = strip + (L >> 8);
    row = row < N ? row : N - 1;
    gll16(gsrc + (size_t)row * 256 + (L & 255), scr + c * 1024 + lane * 16);
  }
}

// linear copy wave scr (32 rows) -> global rows strip.. (predicated, full 64B sectors)
__device__ __forceinline__ void copy_rows_out(const char* scr, char* gdst, int strip, int N, int lane) {
  #pragma unroll
  for (int c = 0; c < 8; ++c) {
    int L = c * 1024 + lane * 16;
    int row = strip + (L >> 8);
    if (row < N) *(uint4*)(gdst + (size_t)strip * 256 + L) = *(const uint4*)(scr + L);
  }
}

__device__ __forceinline__ void zacc82(f32x4 acc[8][2]) {
  #pragma unroll
  for (int m = 0; m < 8; ++m)
    #pragma unroll
    for (int n = 0; n < 2; ++n) { f32x4 z = {0.f,0.f,0.f,0.f}; acc[m][n] = z; }
}

// K=128 GEMM vs [128][128] swizzled slab (LDS); D[ch][node], 32 nodes/wave
__device__ __forceinline__ void gemm128(const char* wbase, const bf16x8 b[2][4],
                                        f32x4 acc[8][2], int l15, int lg) {
  __builtin_amdgcn_s_setprio(1);
  #pragma unroll
  for (int ks = 0; ks < 4; ++ks)
    #pragma unroll
    for (int mf = 0; mf < 8; ++mf) {
      const int row = 16*mf + l15;
      bf16x8 a = *(const bf16x8*)(wbase + row*256 + ((16*lg + 64*ks) ^ ((row&7)<<4)));
      acc[mf][0] = __builtin_amdgcn_mfma_f32_16x16x32_bf16(a, b[0][ks], acc[mf][0], 0,0,0);
      acc[mf][1] = __builtin_amdgcn_mfma_f32_16x16x32_bf16(a, b[1][ks], acc[mf][1], 0,0,0);
    }
  __builtin_amdgcn_s_setprio(0);
}

// read B-frags (activations) from wave-private swizzled scr
__device__ __forceinline__ void read_bfrags(const char* scr, bf16x8 b[2][4], int l15, int lg) {
  #pragma unroll
  for (int nf = 0; nf < 2; ++nf) {
    const int n = 16*nf + l15;
    #pragma unroll
    for (int ks = 0; ks < 4; ++ks)
      b[nf][ks] = *(const bf16x8*)(scr + n*256 + ((16*lg + 64*ks) ^ ((n&7)<<4)));
  }
}

// bias + act -> wave-private scr (swizzled b64 writes)
template<int ACT>  // 0 lrelu, 1 tanh
__device__ __forceinline__ void ep_lds(const f32x4 acc[8][2], const float* __restrict__ bias,
                                       char* scr, int l15, int lg) {
  #pragma unroll
  for (int mf = 0; mf < 8; ++mf) {
    const int ch4 = 16*mf + 4*lg;
    const float4 bv = *(const float4*)(bias + ch4);
    #pragma unroll
    for (int nf = 0; nf < 2; ++nf) {
      const int n = 16*nf + l15;
      float v0 = acc[mf][nf][0]+bv.x, v1 = acc[mf][nf][1]+bv.y;
      float v2 = acc[mf][nf][2]+bv.z, v3 = acc[mf][nf][3]+bv.w;
      if (ACT == 0) { v0=lrelu(v0); v1=lrelu(v1); v2=lrelu(v2); v3=lrelu(v3); }
      else { v0=tanh_fast(v0); v1=tanh_fast(v1); v2=tanh_fast(v2); v3=tanh_fast(v3); }
      uint2 o = { pack2(v0,v1), pack2(v2,v3) };
      *(uint2*)(scr + n*256 + ((32*mf + 8*lg) ^ ((n&7)<<4))) = o;
    }
  }
}

// ---------------- weight pack (f32 -> bf16, pre-swizzled slabs) + deg zero ----------------
extern "C" __global__ void __launch_bounds__(256) wpack_kernel(
    const float* __restrict__ pw0, const float* __restrict__ pw1,
    const float* __restrict__ mw0, const float* __restrict__ mw1, const float* __restrict__ mw2,
    const float* __restrict__ qw0, const float* __restrict__ qw1,
    char* wbf, int* deg, int N) {
  int gid = blockIdx.x * 256 + threadIdx.x;
  if (gid < 13824) {
    int c = gid;
    const float* src = nullptr;
    int dstB = 0;
    bool zero = false;
    if (c < 512) { int r = c >> 2, q = c & 3;
      dstB = OFF_P0 + r*64 + ((q*16) ^ ((r&3)<<4));
      if (q < 2) src = pw0 + r*16 + q*8; else zero = true;
    } else if (c < 2560) { int i = c - 512, r = i >> 4, q = i & 15;
      dstB = OFF_P1 + r*256 + ((q*16) ^ ((r&7)<<4));
      src = pw1 + r*128 + q*8;
    } else if (c < 8704) { int i = c - 2560, sl = i >> 11, j = i & 2047, r = j >> 4, q = j & 15;
      const float* m = (sl==0) ? mw0 : ((sl==1) ? mw1 : mw2);
      dstB = OFF_M0 + sl*32768 + r*256 + ((q*16) ^ ((r&7)<<4));
      src = m + r*128 + q*8;
    } else if (c < 10752) { int i = c - 8704, r = i >> 4, q = i & 15;
      dstB = OFF_Q0A + r*256 + ((q*16) ^ ((r&7)<<4));
      src = qw0 + r*256 + q*8;
    } else if (c < 12800) { int i = c - 10752, r = i >> 4, q = i & 15;
      dstB = OFF_Q0B + r*256 + ((q*16) ^ ((r&7)<<4));
      src = qw0 + r*256 + 128 + q*8;
    } else { int i = c - 12800, r = i >> 4, q = i & 15;
      dstB = OFF_Q1 + r*256 + ((q*16) ^ ((r&7)<<4));
      src = qw1 + r*128 + q*8;
    }
    ushort4 lo, hi;
    if (zero) { lo.x=lo.y=lo.z=lo.w=0; hi.x=hi.y=hi.z=hi.w=0; }
    else {
      float4 a = *(const float4*)src, b = *(const float4*)(src + 4);
      lo.x=f2bf(a.x); lo.y=f2bf(a.y); lo.z=f2bf(a.z); lo.w=f2bf(a.w);
      hi.x=f2bf(b.x); hi.y=f2bf(b.y); hi.z=f2bf(b.z); hi.w=f2bf(b.w);
    }
    *(ushort4*)(wbf + dstB) = lo;
    *(ushort4*)(wbf + dstB + 8) = hi;
  }
  if (gid < N) deg[gid] = 0;
}

// ---------------- prep: x[N,16] -> h; fused dst histogram; P weights LDS-resident ----------------
extern "C" __global__ void __launch_bounds__(512) prep_kernel(
    const float* __restrict__ x,
    const float* __restrict__ pb0, const float* __restrict__ pb1,
    const char* __restrict__ wbf,
    const int* __restrict__ ei, int* deg, int E,
    char* hB, int N, int ntiles) {
  __shared__ char wP[40960];
  __shared__ char scr_all[8 * 8192];
  const int tid = threadIdx.x, lane = tid & 63, wv = tid >> 6;
  const int l15 = lane & 15, lg = lane >> 4;

  gll_lin(wbf + OFF_P0, wP, 40, wv, 8, lane);
  for (int e = blockIdx.x*512 + tid; e < E; e += gridDim.x*512)
    atomicAdd(&deg[ei[E + e]], 1);
  VMCNT0; __syncthreads();
  char* scr = scr_all + wv * 8192;

  for (int tile = blockIdx.x; tile < ntiles; tile += gridDim.x) {
    const int strip = tile*256 + wv*32;
    if (strip >= N) continue;
    // layer 0: K=32 (k>=16 zero), B-frags direct from x
    bf16x8 bx[2];
    #pragma unroll
    for (int nf = 0; nf < 2; ++nf) {
      int node = strip + 16*nf + l15; node = node < N ? node : N-1;
      if (lg < 2) {
        float4 u = *(const float4*)(x + (size_t)node*16 + lg*8);
        float4 v = *(const float4*)(x + (size_t)node*16 + lg*8 + 4);
        bf16x8 t;
        t[0]=(short)f2bf(u.x); t[1]=(short)f2bf(u.y); t[2]=(short)f2bf(u.z); t[3]=(short)f2bf(u.w);
        t[4]=(short)f2bf(v.x); t[5]=(short)f2bf(v.y); t[6]=(short)f2bf(v.z); t[7]=(short)f2bf(v.w);
        bx[nf] = t;
      } else {
        bf16x8 t = {0,0,0,0,0,0,0,0}; bx[nf] = t;
      }
    }
    f32x4 acc[8][2];
    zacc82(acc);
    __builtin_amdgcn_s_setprio(1);
    #pragma unroll
    for (int mf = 0; mf < 8; ++mf) {
      const int row = 16*mf + l15;
      bf16x8 a = *(const bf16x8*)(wP + row*64 + ((16*lg) ^ ((row&3)<<4)));
      acc[mf][0] = __builtin_amdgcn_mfma_f32_16x16x32_bf16(a, bx[0], acc[mf][0], 0,0,0);
      acc[mf][1] = __builtin_amdgcn_mfma_f32_16x16x32_bf16(a, bx[1], acc[mf][1], 0,0,0);
    }
    __builtin_amdgcn_s_setprio(0);
    ep_lds<0>(acc, pb0, scr, l15, lg);
    bf16x8 b1[2][4];
    read_bfrags(scr, b1, l15, lg);
    zacc82(acc);
    gemm128(wP + 8192, b1, acc, l15, lg);
    ep_lds<1>(acc, pb1, scr, l15, lg);
    copy_rows_out(scr, hB, strip, N, lane);
  }
}

// ---------------- CSR scan: 3-kernel multi-block (proven r3-r5; N <= 131072 -> nb1 <= 64) ----------------
extern "C" __global__ void __launch_bounds__(256) scan_partials_kernel(
    const int* __restrict__ deg, int* partials, int N) {
  __shared__ int red[256];
  int b = blockIdx.x, t = threadIdx.x;
  int base = b * 2048 + t * 8, s = 0;
  #pragma unroll
  for (int i = 0; i < 8; ++i) { int idx = base + i; s += (idx < N) ? deg[idx] : 0; }
  red[t] = s; __syncthreads();
  for (int off = 128; off > 0; off >>= 1) {
    if (t < off) red[t] += red[t + off];
    __syncthreads();
  }
  if (t == 0) partials[b] = red[0];
}

extern "C" __global__ void scan_base_kernel(const int* __restrict__ partials, int* basearr, int nb) {
  int lane = threadIdx.x;
  int orig = (lane < nb) ? partials[lane] : 0;
  int v = orig;
  #pragma unroll
  for (int off = 1; off < 64; off <<= 1) {
    int u = __shfl_up(v, off);
    if (lane >= off) v += u;
  }
  if (lane < nb) basearr[lane] = v - orig;  // exclusive
}

extern "C" __global__ void __launch_bounds__(256) scan_apply_kernel(
    const int* __restrict__ deg, const int* __restrict__ basearr,
    int* offs, int* cur, int N) {
  __shared__ int sc[256];
  int b = blockIdx.x, t = threadIdx.x;
  int base = b * 2048 + t * 8;
  int loc[8], s = 0;
  #pragma unroll
  for (int i = 0; i < 8; ++i) { int idx = base + i; loc[i] = (idx < N) ? deg[idx] : 0; s += loc[i]; }
  sc[t] = s; __syncthreads();
  for (int off = 1; off < 256; off <<= 1) {
    int v = sc[t];
    int u = (t >= off) ? sc[t - off] : 0;
    __syncthreads();
    sc[t] = v + u;
    __syncthreads();
  }
  int run = basearr[b] + ((t == 0) ? 0 : sc[t - 1]);
  #pragma unroll
  for (int i = 0; i < 8; ++i) {
    int idx = base + i;
    if (idx < N) { offs[idx] = run; cur[idx] = run; run += loc[i]; }
  }
}

extern "C" __global__ void __launch_bounds__(256) scatter_kernel(
    const int* __restrict__ ei, const float* __restrict__ ew,
    int* cur, int2* recs, int E) {
  int e = blockIdx.x * 256 + threadIdx.x;
  if (e < E) {
    int dst = ei[E + e];
    int slot = atomicAdd(&cur[dst], 1);
    int2 r; r.x = ei[e]; r.y = __float_as_int(ew[e]);
    recs[slot] = r;
  }
}

// ---------------- aggregation: z = h_dst + sum relu(h_src + w*elw + elb) ----------------
extern "C" __global__ void __launch_bounds__(256) agg_kernel(
    const int* __restrict__ offs, const int* __restrict__ cur,
    const int2* __restrict__ recs,
    const float* __restrict__ elw, const float* __restrict__ elb,
    const char* __restrict__ hB, char* zB, int N) {
  const int lane = threadIdx.x & 63, wv = threadIdx.x >> 6;
  const int node = blockIdx.x * 4 + wv;
  if (node >= N) return;
  const float2 wl = *(const float2*)(elw + 2*lane);
  const float2 bl = *(const float2*)(elb + 2*lane);
  const int byteL = lane * 4;
  const int s = offs[node], e = cur[node];
  float c0 = 0.f, c1 = 0.f;
  int j = s;
  for (; j + 4 <= e; j += 4) {
    int2 r0 = recs[j], r1 = recs[j+1], r2 = recs[j+2], r3 = recs[j+3];
    unsigned u0 = *(const unsigned*)(hB + (size_t)r0.x*256 + (byteL ^ ((r0.x&7)<<4)));
    unsigned u1 = *(const unsigned*)(hB + (size_t)r1.x*256 + (byteL ^ ((r1.x&7)<<4)));
    unsigned u2 = *(const unsigned*)(hB + (size_t)r2.x*256 + (byteL ^ ((r2.x&7)<<4)));
    unsigned u3 = *(const unsigned*)(hB + (size_t)r3.x*256 + (byteL ^ ((r3.x&7)<<4)));
    float w0 = __int_as_float(r0.y), w1 = __int_as_float(r1.y);
    float w2 = __int_as_float(r2.y), w3 = __int_as_float(r3.y);
    c0 += fmaxf(bflo(u0) + w0*wl.x + bl.x, 0.f); c1 += fmaxf(bfhi(u0) + w0*wl.y + bl.y, 0.f);
    c0 += fmaxf(bflo(u1) + w1*wl.x + bl.x, 0.f); c1 += fmaxf(bfhi(u1) + w1*wl.y + bl.y, 0.f);
    c0 += fmaxf(bflo(u2) + w2*wl.x + bl.x, 0.f); c1 += fmaxf(bfhi(u2) + w2*wl.y + bl.y, 0.f);
    c0 += fmaxf(bflo(u3) + w3*wl.x + bl.x, 0.f); c1 += fmaxf(bfhi(u3) + w3*wl.y + bl.y, 0.f);
  }
  for (; j < e; ++j) {
    int2 r = recs[j];
    unsigned u = *(const unsigned*)(hB + (size_t)r.x*256 + (byteL ^ ((r.x&7)<<4)));
    float w = __int_as_float(r.y);
    c0 += fmaxf(bflo(u) + w*wl.x + bl.x, 0.f);
    c1 += fmaxf(bfhi(u) + w*wl.y + bl.y, 0.f);
  }
  unsigned hs = *(const unsigned*)(hB + (size_t)node*256 + (byteL ^ ((node&7)<<4)));
  unsigned o = pack2(bflo(hs) + c0, bfhi(hs) + c1);
  *(unsigned*)(zB + (size_t)node*256 + (byteL ^ ((node&7)<<4))) = o;
}

// ---------------- node MLP part A: z -> z3 (mw0,mw1,mw2 LDS-resident; persistent) ----------------
extern "C" __global__ void __launch_bounds__(448) nodeA_kernel(
    const char* __restrict__ zB, const char* __restrict__ wbf,
    const float* __restrict__ mb0, const float* __restrict__ mb1, const float* __restrict__ mb2,
    char* z3, int N, int ntiles) {
  __shared__ char wM[98304];
  __shared__ char scr_all[7 * 8192];
  const int tid = threadIdx.x, lane = tid & 63, wv = tid >> 6;
  const int l15 = lane & 15, lg = lane >> 4;

  gll_lin(wbf + OFF_M0, wM, 96, wv, 7, lane);
  VMCNT0; __syncthreads();
  char* scr = scr_all + wv * 8192;

  for (int tile = blockIdx.x; tile < ntiles; tile += gridDim.x) {
    const int strip = tile*224 + wv*32;
    if (strip >= N) continue;
    gll_rows(zB, scr, strip, N, lane);
    VMCNT0;
    bf16x8 b0[2][4];
    read_bfrags(scr, b0, l15, lg);
    f32x4 acc[8][2];
    zacc82(acc);
    gemm128(wM, b0, acc, l15, lg);
    ep_lds<0>(acc, mb0, scr, l15, lg);
    bf16x8 b1[2][4];
    read_bfrags(scr, b1, l15, lg);
    zacc82(acc);
    gemm128(wM + 32768, b1, acc, l15, lg);
    ep_lds<0>(acc, mb1, scr, l15, lg);
    bf16x8 b2[2][4];
    read_bfrags(scr, b2, l15, lg);
    zacc82(acc);
    gemm128(wM + 65536, b2, acc, l15, lg);
    ep_lds<1>(acc, mb2, scr, l15, lg);
    copy_rows_out(scr, z3, strip, N, lane);
  }
}

// ---------------- node MLP part B: [z3 | h] -> post -> out (Q slabs LDS-resident; persistent) ----------------
extern "C" __global__ void __launch_bounds__(512) nodeB_kernel(
    const char* __restrict__ z3, const char* hB, const char* __restrict__ wbf,
    const float* __restrict__ qb0, const float* __restrict__ qb1,
    float* out, int N, int ntiles) {
  __shared__ char wQ[81920];         // Q0a @0, Q0b @32768, Q1 @65536
  __shared__ char scr_all[8 * 8192];
  const int tid = threadIdx.x, lane = tid & 63, wv = tid >> 6;
  const int l15 = lane & 15, lg = lane >> 4;

  gll_lin(wbf + OFF_Q0A, wQ, 80, wv, 8, lane);
  VMCNT0; __syncthreads();
  char* scr = scr_all + wv * 8192;

  for (int tile = blockIdx.x; tile < ntiles; tile += gridDim.x) {
    const int strip = tile*256 + wv*32;
    if (strip >= N) continue;
    gll_rows(z3, scr, strip, N, lane);
    // h B-frags gathered directly from global while z3 stage is in flight
    bf16x8 bh[2][4];
    #pragma unroll
    for (int nf = 0; nf < 2; ++nf) {
      int node = strip + 16*nf + l15; node = node < N ? node : N-1;
      const char* hr = hB + (size_t)node*256;
      const int sw = (node&7) << 4;
      #pragma unroll
      for (int ks = 0; ks < 4; ++ks)
        bh[nf][ks] = *(const bf16x8*)(hr + ((16*lg + 64*ks) ^ sw));
    }
    VMCNT0;
    bf16x8 bz[2][4];
    read_bfrags(scr, bz, l15, lg);
    f32x4 acc[8][2];
    zacc82(acc);
    gemm128(wQ, bz, acc, l15, lg);          // qw0a @ z3
    gemm128(wQ + 32768, bh, acc, l15, lg);  // += qw0b @ h
    ep_lds<0>(acc, qb0, scr, l15, lg);      // lrelu -> t

    bf16x8 bt[2][4];
    read_bfrags(scr, bt, l15, lg);
    f32x4 a2[4][2];
    #pragma unroll
    for (int m = 0; m < 4; ++m)
      #pragma unroll
      for (int n = 0; n < 2; ++n) { f32x4 z = {0.f,0.f,0.f,0.f}; a2[m][n] = z; }
    __builtin_amdgcn_s_setprio(1);
    #pragma unroll
    for (int ks = 0; ks < 4; ++ks)
      #pragma unroll
      for (int mf = 0; mf < 4; ++mf) {
        const int row = 16*mf + l15;
        bf16x8 a = *(const bf16x8*)(wQ + 65536 + row*256 + ((16*lg + 64*ks) ^ ((row&7)<<4)));
        a2[mf][0] = __builtin_amdgcn_mfma_f32_16x16x32_bf16(a, bt[0][ks], a2[mf][0], 0,0,0);
        a2[mf][1] = __builtin_amdgcn_mfma_f32_16x16x32_bf16(a, bt[1][ks], a2[mf][1], 0,0,0);
      }
    __builtin_amdgcn_s_setprio(0);
    #pragma unroll
    for (int mf = 0; mf < 4; ++mf) {
      const int ch4 = 16*mf + 4*lg;
      const float4 bv = *(const float4*)(qb1 + ch4);
      #pragma unroll
      for (int nf = 0; nf < 2; ++nf) {
        const int node = strip + 16*nf + l15;
        if (node < N) {
          float4 o;
          o.x = tanh_fast(a2[mf][nf][0] + bv.x);
          o.y = tanh_fast(a2[mf][nf][1] + bv.y);
          o.z = tanh_fast(a2[mf][nf][2] + bv.z);
          o.w = tanh_fast(a2[mf][nf][3] + bv.w);
          *(float4*)(out + (size_t)node*64 + ch4) = o;
        }
      }
    }
  }
}

extern "C" void kernel_launch(void* const* d_in, const int* in_sizes, int n_in,
                              void* d_out, int out_size, void* d_ws, size_t ws_size,
                              hipStream_t stream) {
  const float* x   = (const float*)d_in[0];
  const int*   ei  = (const int*)d_in[1];
  const float* ew  = (const float*)d_in[2];
  const float* pw0 = (const float*)d_in[3];
  const float* pb0 = (const float*)d_in[4];
  const float* pw1 = (const float*)d_in[5];
  const float* pb1 = (const float*)d_in[6];
  const float* elw = (const float*)d_in[7];
  const float* elb = (const float*)d_in[8];
  const float* mw0 = (const float*)d_in[9];
  const float* mb0 = (const float*)d_in[10];
  const float* mw1 = (const float*)d_in[11];
  const float* mb1 = (const float*)d_in[12];
  const float* mw2 = (const float*)d_in[13];
  const float* mb2 = (const float*)d_in[14];
  const float* qw0 = (const float*)d_in[15];
  const float* qb0 = (const float*)d_in[16];
  const float* qw1 = (const float*)d_in[17];
  const float* qb1 = (const float*)d_in[18];
  float* out = (float*)d_out;

  const int N = in_sizes[0] / 16;
  const int E = in_sizes[1] / 2;

  char* p = (char*)d_ws;
  auto alloc = [&](size_t bytes) { char* r = p; p += (bytes + 255) & ~(size_t)255; return r; };
  const size_t rowBytes = (size_t)N * 256;

  char* zB      = alloc(rowBytes);           // bf16 [N][128], swizzled content
  char* z3      = alloc(rowBytes);           // bf16 [N][128], swizzled content
  int2* recs    = (int2*)alloc((size_t)E * 8);
  int*  deg     = (int*)alloc((size_t)N * 4);
  int*  offs    = (int*)alloc((size_t)N * 4);
  int*  cur     = (int*)alloc((size_t)N * 4);
  int*  part    = (int*)alloc(256 * 4);
  int*  basearr = (int*)alloc(256 * 4);
  char* wbf     = alloc(WBF_BYTES);

  char* hB;
  if ((size_t)(p - (char*)d_ws) + rowBytes <= ws_size) {
    hB = alloc(rowBytes);
  } else {
    hB = (char*)d_out;  // alias: each node's h row read before that node's out write
  }

  const int ntilesP = (N + 255) / 256;
  const int ntilesA = (N + 223) / 224;
  const int ntilesB = (N + 255) / 256;
  const int nb1  = (N + 2047) / 2048;   // <= 64 for N <= 131072
  const int eblk = (E + 255) / 256;
  const int pgrid = ((13824 > N ? 13824 : N) + 255) / 256;

  wpack_kernel<<<dim3(pgrid), dim3(256), 0, stream>>>(pw0, pw1, mw0, mw1, mw2, qw0, qw1,
                                                      wbf, deg, N);
  prep_kernel<<<dim3(256), dim3(512), 0, stream>>>(x, pb0, pb1, wbf, ei, deg, E, hB, N, ntilesP);
  scan_partials_kernel<<<dim3(nb1), dim3(256), 0, stream>>>(deg, part, N);
  scan_base_kernel<<<dim3(1), dim3(64), 0, stream>>>(part, basearr, nb1);
  scan_apply_kernel<<<dim3(nb1), dim3(256), 0, stream>>>(deg, basearr, offs, cur, N);
  scatter_kernel<<<dim3(eblk), dim3(256), 0, stream>>>(ei, ew, cur, recs, E);
  agg_kernel<<<dim3((N + 3) / 4), dim3(256), 0, stream>>>(offs, cur, recs, elw, elb, hB, zB, N);
  nodeA_kernel<<<dim3(256), dim3(448), 0, stream>>>(zB, wbf, mb0, mb1, mb2, z3, N, ntilesA);
  nodeB_kernel<<<dim3(256), dim3(512), 0, stream>>>(z3, hB, wbf, qb0, qb1, out, N, ntilesB);
}

// Round 9
// 244.073 us; speedup vs baseline: 1.4160x; 1.0624x over previous
//
#include <hip/hip_runtime.h>

typedef short bf16x8 __attribute__((ext_vector_type(8)));
typedef float f32x4 __attribute__((ext_vector_type(4)));

#define NEG 0.01f

// wbf slab byte offsets (bf16, content pre-swizzled within rows: byte ^= (row&KEY)<<4, 16B granule)
#define OFF_P0  0        // [128][32]  rowB=64,  key (r&3)<<4 (pw0, k padded 16->32 with zeros)
#define OFF_P1  8192     // [128][128] rowB=256, key (r&7)<<4
#define OFF_M0  40960    // [128][128] x3 (mw0,mw1,mw2)
#define OFF_Q0A 139264   // [128][128] qw0 cols 0..127   (z3 part)
#define OFF_Q0B 172032   // [128][128] qw0 cols 128..255 (h part)
#define OFF_Q1  204800   // [64][128]
#define WBF_BYTES 221184

#define VMCNT0 asm volatile("s_waitcnt vmcnt(0)" ::: "memory")

__device__ __forceinline__ unsigned short f2bf(float f) {
  union { float f; unsigned u; } v; v.f = f;
  unsigned u = v.u;
  return (unsigned short)((u + 0x7fffu + ((u >> 16) & 1u)) >> 16);
}
__device__ __forceinline__ unsigned pack2(float a, float b) {
  return ((unsigned)f2bf(b) << 16) | (unsigned)f2bf(a);
}
__device__ __forceinline__ float bflo(unsigned u) { return __uint_as_float(u << 16); }
__device__ __forceinline__ float bfhi(unsigned u) { return __uint_as_float(u & 0xffff0000u); }
__device__ __forceinline__ float lrelu(float v) { return fmaxf(v, 0.0f) + NEG * fminf(v, 0.0f); }
__device__ __forceinline__ float tanh_fast(float x) {
  float e = __expf(2.0f * x);
  return 1.0f - __fdividef(2.0f, e + 1.0f);
}

// async global->LDS, 16B per lane (LDS dest = wave-uniform base + lane*16)
__device__ __forceinline__ void gll16(const void* g, void* l) {
  __builtin_amdgcn_global_load_lds((const __attribute__((address_space(1))) void*)g,
                                   (__attribute__((address_space(3))) void*)l, 16, 0, 0);
}

// linear slab stage: nchunks 1KB chunks, wave j owns chunks j, j+nw, ...
__device__ __forceinline__ void gll_lin(const char* g, char* l, int nchunks, int wv, int nw, int lane) {
  for (int j = wv; j < nchunks; j += nw)
    gll16(g + j * 1024 + lane * 16, l + j * 1024 + lane * 16);
}

// stage 32 rows (256B each, swizzled content) from global into wave-private scr (linear)
__device__ __forceinline__ void gll_rows(const char* gsrc, char* scr, int strip, int N, int lane) {
  #pragma unroll
  for (int c = 0; c < 8; ++c) {
    int L = c * 1024 + lane * 16;
    int row = strip + (L >> 8);
    row = row < N ? row : N - 1;
    gll16(gsrc + (size_t)row * 256 + (L & 255), scr + c * 1024 + lane * 16);
  }
}

// linear copy wave scr (32 rows) -> global rows strip.. (predicated, full 64B sectors)
__device__ __forceinline__ void copy_rows_out(const char* scr, char* gdst, int strip, int N, int lane) {
  #pragma unroll
  for (int c = 0; c < 8; ++c) {
    int L = c * 1024 + lane * 16;
    int row = strip + (L >> 8);
    if (row < N) *(uint4*)(gdst + (size_t)strip * 256 + L) = *(const uint4*)(scr + L);
  }
}

__device__ __forceinline__ void zacc82(f32x4 acc[8][2]) {
  #pragma unroll
  for (int m = 0; m < 8; ++m)
    #pragma unroll
    for (int n = 0; n < 2; ++n) { f32x4 z = {0.f,0.f,0.f,0.f}; acc[m][n] = z; }
}

// K=128 GEMM vs [128][128] swizzled slab (LDS); D[ch][node], 32 nodes/wave
__device__ __forceinline__ void gemm128(const char* wbase, const bf16x8 b[2][4],
                                        f32x4 acc[8][2], int l15, int lg) {
  __builtin_amdgcn_s_setprio(1);
  #pragma unroll
  for (int ks = 0; ks < 4; ++ks)
    #pragma unroll
    for (int mf = 0; mf < 8; ++mf) {
      const int row = 16*mf + l15;
      bf16x8 a = *(const bf16x8*)(wbase + row*256 + ((16*lg + 64*ks) ^ ((row&7)<<4)));
      acc[mf][0] = __builtin_amdgcn_mfma_f32_16x16x32_bf16(a, b[0][ks], acc[mf][0], 0,0,0);
      acc[mf][1] = __builtin_amdgcn_mfma_f32_16x16x32_bf16(a, b[1][ks], acc[mf][1], 0,0,0);
    }
  __builtin_amdgcn_s_setprio(0);
}

// read B-frags (activations) from wave-private swizzled scr
__device__ __forceinline__ void read_bfrags(const char* scr, bf16x8 b[2][4], int l15, int lg) {
  #pragma unroll
  for (int nf = 0; nf < 2; ++nf) {
    const int n = 16*nf + l15;
    #pragma unroll
    for (int ks = 0; ks < 4; ++ks)
      b[nf][ks] = *(const bf16x8*)(scr + n*256 + ((16*lg + 64*ks) ^ ((n&7)<<4)));
  }
}

// bias + act -> wave-private scr (swizzled b64 writes)
template<int ACT>  // 0 lrelu, 1 tanh
__device__ __forceinline__ void ep_lds(const f32x4 acc[8][2], const float* __restrict__ bias,
                                       char* scr, int l15, int lg) {
  #pragma unroll
  for (int mf = 0; mf < 8; ++mf) {
    const int ch4 = 16*mf + 4*lg;
    const float4 bv = *(const float4*)(bias + ch4);
    #pragma unroll
    for (int nf = 0; nf < 2; ++nf) {
      const int n = 16*nf + l15;
      float v0 = acc[mf][nf][0]+bv.x, v1 = acc[mf][nf][1]+bv.y;
      float v2 = acc[mf][nf][2]+bv.z, v3 = acc[mf][nf][3]+bv.w;
      if (ACT == 0) { v0=lrelu(v0); v1=lrelu(v1); v2=lrelu(v2); v3=lrelu(v3); }
      else { v0=tanh_fast(v0); v1=tanh_fast(v1); v2=tanh_fast(v2); v3=tanh_fast(v3); }
      uint2 o = { pack2(v0,v1), pack2(v2,v3) };
      *(uint2*)(scr + n*256 + ((32*mf + 8*lg) ^ ((n&7)<<4))) = o;
    }
  }
}

// ---------------- weight pack (f32 -> bf16, pre-swizzled slabs) + deg zero ----------------
extern "C" __global__ void __launch_bounds__(256) wpack_kernel(
    const float* __restrict__ pw0, const float* __restrict__ pw1,
    const float* __restrict__ mw0, const float* __restrict__ mw1, const float* __restrict__ mw2,
    const float* __restrict__ qw0, const float* __restrict__ qw1,
    char* wbf, int* deg, int N) {
  int gid = blockIdx.x * 256 + threadIdx.x;
  if (gid < 13824) {
    int c = gid;
    const float* src = nullptr;
    int dstB = 0;
    bool zero = false;
    if (c < 512) { int r = c >> 2, q = c & 3;
      dstB = OFF_P0 + r*64 + ((q*16) ^ ((r&3)<<4));
      if (q < 2) src = pw0 + r*16 + q*8; else zero = true;
    } else if (c < 2560) { int i = c - 512, r = i >> 4, q = i & 15;
      dstB = OFF_P1 + r*256 + ((q*16) ^ ((r&7)<<4));
      src = pw1 + r*128 + q*8;
    } else if (c < 8704) { int i = c - 2560, sl = i >> 11, j = i & 2047, r = j >> 4, q = j & 15;
      const float* m = (sl==0) ? mw0 : ((sl==1) ? mw1 : mw2);
      dstB = OFF_M0 + sl*32768 + r*256 + ((q*16) ^ ((r&7)<<4));
      src = m + r*128 + q*8;
    } else if (c < 10752) { int i = c - 8704, r = i >> 4, q = i & 15;
      dstB = OFF_Q0A + r*256 + ((q*16) ^ ((r&7)<<4));
      src = qw0 + r*256 + q*8;
    } else if (c < 12800) { int i = c - 10752, r = i >> 4, q = i & 15;
      dstB = OFF_Q0B + r*256 + ((q*16) ^ ((r&7)<<4));
      src = qw0 + r*256 + 128 + q*8;
    } else { int i = c - 12800, r = i >> 4, q = i & 15;
      dstB = OFF_Q1 + r*256 + ((q*16) ^ ((r&7)<<4));
      src = qw1 + r*128 + q*8;
    }
    ushort4 lo, hi;
    if (zero) { lo.x=lo.y=lo.z=lo.w=0; hi.x=hi.y=hi.z=hi.w=0; }
    else {
      float4 a = *(const float4*)src, b = *(const float4*)(src + 4);
      lo.x=f2bf(a.x); lo.y=f2bf(a.y); lo.z=f2bf(a.z); lo.w=f2bf(a.w);
      hi.x=f2bf(b.x); hi.y=f2bf(b.y); hi.z=f2bf(b.z); hi.w=f2bf(b.w);
    }
    *(ushort4*)(wbf + dstB) = lo;
    *(ushort4*)(wbf + dstB + 8) = hi;
  }
  if (gid < N) deg[gid] = 0;
}

// ---------------- prep: x[N,16] -> h; fused dst histogram; 256 thr, 72KB -> 2 blocks/CU ----------------
extern "C" __global__ void __launch_bounds__(256, 2) prep_kernel(
    const float* __restrict__ x,
    const float* __restrict__ pb0, const float* __restrict__ pb1,
    const char* __restrict__ wbf,
    const int* __restrict__ ei, int* deg, int E,
    char* hB, int N) {
  __shared__ char wP[40960];
  __shared__ char scr_all[4 * 8192];
  const int tid = threadIdx.x, lane = tid & 63, wv = tid >> 6;
  const int l15 = lane & 15, lg = lane >> 4;

  gll_lin(wbf + OFF_P0, wP, 40, wv, 4, lane);
  for (int e = blockIdx.x*256 + tid; e < E; e += gridDim.x*256)
    atomicAdd(&deg[ei[E + e]], 1);
  VMCNT0; __syncthreads();
  char* scr = scr_all + wv * 8192;

  const int strip = blockIdx.x*128 + wv*32;
  if (strip >= N) return;

  // layer 0: K=32 (k>=16 zero), B-frags direct from x
  bf16x8 bx[2];
  #pragma unroll
  for (int nf = 0; nf < 2; ++nf) {
    int node = strip + 16*nf + l15; node = node < N ? node : N-1;
    if (lg < 2) {
      float4 u = *(const float4*)(x + (size_t)node*16 + lg*8);
      float4 v = *(const float4*)(x + (size_t)node*16 + lg*8 + 4);
      bf16x8 t;
      t[0]=(short)f2bf(u.x); t[1]=(short)f2bf(u.y); t[2]=(short)f2bf(u.z); t[3]=(short)f2bf(u.w);
      t[4]=(short)f2bf(v.x); t[5]=(short)f2bf(v.y); t[6]=(short)f2bf(v.z); t[7]=(short)f2bf(v.w);
      bx[nf] = t;
    } else {
      bf16x8 t = {0,0,0,0,0,0,0,0}; bx[nf] = t;
    }
  }
  f32x4 acc[8][2];
  zacc82(acc);
  __builtin_amdgcn_s_setprio(1);
  #pragma unroll
  for (int mf = 0; mf < 8; ++mf) {
    const int row = 16*mf + l15;
    bf16x8 a = *(const bf16x8*)(wP + row*64 + ((16*lg) ^ ((row&3)<<4)));
    acc[mf][0] = __builtin_amdgcn_mfma_f32_16x16x32_bf16(a, bx[0], acc[mf][0], 0,0,0);
    acc[mf][1] = __builtin_amdgcn_mfma_f32_16x16x32_bf16(a, bx[1], acc[mf][1], 0,0,0);
  }
  __builtin_amdgcn_s_setprio(0);
  ep_lds<0>(acc, pb0, scr, l15, lg);
  bf16x8 b1[2][4];
  read_bfrags(scr, b1, l15, lg);
  zacc82(acc);
  gemm128(wP + 8192, b1, acc, l15, lg);
  ep_lds<1>(acc, pb1, scr, l15, lg);
  copy_rows_out(scr, hB, strip, N, lane);
}

// ---------------- CSR scan: partials + apply (base folded into apply; nb1 <= 64) ----------------
extern "C" __global__ void __launch_bounds__(256) scan_partials_kernel(
    const int* __restrict__ deg, int* partials, int N) {
  __shared__ int red[256];
  int b = blockIdx.x, t = threadIdx.x;
  int base = b * 2048 + t * 8, s = 0;
  #pragma unroll
  for (int i = 0; i < 8; ++i) { int idx = base + i; s += (idx < N) ? deg[idx] : 0; }
  red[t] = s; __syncthreads();
  for (int off = 128; off > 0; off >>= 1) {
    if (t < off) red[t] += red[t + off];
    __syncthreads();
  }
  if (t == 0) partials[b] = red[0];
}

extern "C" __global__ void __launch_bounds__(256) scan_apply_kernel(
    const int* __restrict__ deg, const int* __restrict__ partials,
    int* offs, int* cur, int N, int nb) {
  __shared__ int sc[256];
  __shared__ int baseSh;
  int b = blockIdx.x, t = threadIdx.x;
  // wave 0 reduces partials[0..b-1]
  if (t < 64) {
    int v = (t < b && t < nb) ? partials[t] : 0;
    #pragma unroll
    for (int off = 32; off > 0; off >>= 1) v += __shfl_xor(v, off);
    if (t == 0) baseSh = v;
  }
  int base = b * 2048 + t * 8;
  int loc[8], s = 0;
  #pragma unroll
  for (int i = 0; i < 8; ++i) { int idx = base + i; loc[i] = (idx < N) ? deg[idx] : 0; s += loc[i]; }
  sc[t] = s; __syncthreads();
  for (int off = 1; off < 256; off <<= 1) {
    int v = sc[t];
    int u = (t >= off) ? sc[t - off] : 0;
    __syncthreads();
    sc[t] = v + u;
    __syncthreads();
  }
  int run = baseSh + ((t == 0) ? 0 : sc[t - 1]);
  #pragma unroll
  for (int i = 0; i < 8; ++i) {
    int idx = base + i;
    if (idx < N) { offs[idx] = run; cur[idx] = run; run += loc[i]; }
  }
}

extern "C" __global__ void __launch_bounds__(256) scatter_kernel(
    const int* __restrict__ ei, const float* __restrict__ ew,
    int* cur, int2* recs, int E) {
  int e = blockIdx.x * 256 + threadIdx.x;
  if (e < E) {
    int dst = ei[E + e];
    int slot = atomicAdd(&cur[dst], 1);
    int2 r; r.x = ei[e]; r.y = __float_as_int(ew[e]);
    recs[slot] = r;
  }
}

// ---------------- aggregation: half-wave per node (32 lanes x 8B = one 256B row) ----------------
extern "C" __global__ void __launch_bounds__(256) agg_kernel(
    const int* __restrict__ offs, const int* __restrict__ cur,
    const int2* __restrict__ recs,
    const float* __restrict__ elw, const float* __restrict__ elb,
    const char* __restrict__ hB, char* zB, int N) {
  const int lane = threadIdx.x & 63, wv = threadIdx.x >> 6;
  const int half = lane >> 5, l31 = lane & 31;
  const int node = blockIdx.x * 8 + wv * 2 + half;
  if (node >= N) return;
  const float4 wl = *(const float4*)(elw + 4*l31);
  const float4 bl = *(const float4*)(elb + 4*l31);
  const int byteL = l31 * 8;
  const int s = offs[node], e = cur[node];
  float c0 = 0.f, c1 = 0.f, c2 = 0.f, c3 = 0.f;
  int j = s;
  for (; j + 2 <= e; j += 2) {
    int2 r0 = recs[j], r1 = recs[j+1];
    uint2 u0 = *(const uint2*)(hB + (size_t)r0.x*256 + (byteL ^ ((r0.x&7)<<4)));
    uint2 u1 = *(const uint2*)(hB + (size_t)r1.x*256 + (byteL ^ ((r1.x&7)<<4)));
    float w0 = __int_as_float(r0.y), w1 = __int_as_float(r1.y);
    c0 += fmaxf(bflo(u0.x) + w0*wl.x + bl.x, 0.f);
    c1 += fmaxf(bfhi(u0.x) + w0*wl.y + bl.y, 0.f);
    c2 += fmaxf(bflo(u0.y) + w0*wl.z + bl.z, 0.f);
    c3 += fmaxf(bfhi(u0.y) + w0*wl.w + bl.w, 0.f);
    c0 += fmaxf(bflo(u1.x) + w1*wl.x + bl.x, 0.f);
    c1 += fmaxf(bfhi(u1.x) + w1*wl.y + bl.y, 0.f);
    c2 += fmaxf(bflo(u1.y) + w1*wl.z + bl.z, 0.f);
    c3 += fmaxf(bfhi(u1.y) + w1*wl.w + bl.w, 0.f);
  }
  if (j < e) {
    int2 r = recs[j];
    uint2 u = *(const uint2*)(hB + (size_t)r.x*256 + (byteL ^ ((r.x&7)<<4)));
    float w = __int_as_float(r.y);
    c0 += fmaxf(bflo(u.x) + w*wl.x + bl.x, 0.f);
    c1 += fmaxf(bfhi(u.x) + w*wl.y + bl.y, 0.f);
    c2 += fmaxf(bflo(u.y) + w*wl.z + bl.z, 0.f);
    c3 += fmaxf(bfhi(u.y) + w*wl.w + bl.w, 0.f);
  }
  const int swz = byteL ^ ((node&7)<<4);
  uint2 hs = *(const uint2*)(hB + (size_t)node*256 + swz);
  uint2 o;
  o.x = pack2(bflo(hs.x) + c0, bfhi(hs.x) + c1);
  o.y = pack2(bflo(hs.y) + c2, bfhi(hs.y) + c3);
  *(uint2*)(zB + (size_t)node*256 + swz) = o;
}

// ---------------- node MLP part A: z -> z3 (mw0,mw1,mw2 LDS-resident; persistent) ----------------
extern "C" __global__ void __launch_bounds__(448) nodeA_kernel(
    const char* __restrict__ zB, const char* __restrict__ wbf,
    const float* __restrict__ mb0, const float* __restrict__ mb1, const float* __restrict__ mb2,
    char* z3, int N, int ntiles) {
  __shared__ char wM[98304];
  __shared__ char scr_all[7 * 8192];
  const int tid = threadIdx.x, lane = tid & 63, wv = tid >> 6;
  const int l15 = lane & 15, lg = lane >> 4;

  gll_lin(wbf + OFF_M0, wM, 96, wv, 7, lane);
  VMCNT0; __syncthreads();
  char* scr = scr_all + wv * 8192;

  for (int tile = blockIdx.x; tile < ntiles; tile += gridDim.x) {
    const int strip = tile*224 + wv*32;
    if (strip >= N) continue;
    gll_rows(zB, scr, strip, N, lane);
    VMCNT0;
    bf16x8 b0[2][4];
    read_bfrags(scr, b0, l15, lg);
    f32x4 acc[8][2];
    zacc82(acc);
    gemm128(wM, b0, acc, l15, lg);
    ep_lds<0>(acc, mb0, scr, l15, lg);
    bf16x8 b1[2][4];
    read_bfrags(scr, b1, l15, lg);
    zacc82(acc);
    gemm128(wM + 32768, b1, acc, l15, lg);
    ep_lds<0>(acc, mb1, scr, l15, lg);
    bf16x8 b2[2][4];
    read_bfrags(scr, b2, l15, lg);
    zacc82(acc);
    gemm128(wM + 65536, b2, acc, l15, lg);
    ep_lds<1>(acc, mb2, scr, l15, lg);
    copy_rows_out(scr, z3, strip, N, lane);
  }
}

// ---------------- node MLP part B: [z3 | h] -> post -> out (Q slabs LDS-resident; persistent) ----------------
extern "C" __global__ void __launch_bounds__(512) nodeB_kernel(
    const char* __restrict__ z3, const char* hB, const char* __restrict__ wbf,
    const float* __restrict__ qb0, const float* __restrict__ qb1,
    float* out, int N, int ntiles) {
  __shared__ char wQ[81920];         // Q0a @0, Q0b @32768, Q1 @65536
  __shared__ char scr_all[8 * 8192];
  const int tid = threadIdx.x, lane = tid & 63, wv = tid >> 6;
  const int l15 = lane & 15, lg = lane >> 4;

  gll_lin(wbf + OFF_Q0A, wQ, 80, wv, 8, lane);
  VMCNT0; __syncthreads();
  char* scr = scr_all + wv * 8192;

  for (int tile = blockIdx.x; tile < ntiles; tile += gridDim.x) {
    const int strip = tile*256 + wv*32;
    if (strip >= N) continue;
    gll_rows(z3, scr, strip, N, lane);
    // h B-frags gathered directly from global while z3 stage is in flight
    bf16x8 bh[2][4];
    #pragma unroll
    for (int nf = 0; nf < 2; ++nf) {
      int node = strip + 16*nf + l15; node = node < N ? node : N-1;
      const char* hr = hB + (size_t)node*256;
      const int sw = (node&7) << 4;
      #pragma unroll
      for (int ks = 0; ks < 4; ++ks)
        bh[nf][ks] = *(const bf16x8*)(hr + ((16*lg + 64*ks) ^ sw));
    }
    VMCNT0;
    bf16x8 bz[2][4];
    read_bfrags(scr, bz, l15, lg);
    f32x4 acc[8][2];
    zacc82(acc);
    gemm128(wQ, bz, acc, l15, lg);          // qw0a @ z3
    gemm128(wQ + 32768, bh, acc, l15, lg);  // += qw0b @ h
    ep_lds<0>(acc, qb0, scr, l15, lg);      // lrelu -> t

    bf16x8 bt[2][4];
    read_bfrags(scr, bt, l15, lg);
    f32x4 a2[4][2];
    #pragma unroll
    for (int m = 0; m < 4; ++m)
      #pragma unroll
      for (int n = 0; n < 2; ++n) { f32x4 z = {0.f,0.f,0.f,0.f}; a2[m][n] = z; }
    __builtin_amdgcn_s_setprio(1);
    #pragma unroll
    for (int ks = 0; ks < 4; ++ks)
      #pragma unroll
      for (int mf = 0; mf < 4; ++mf) {
        const int row = 16*mf + l15;
        bf16x8 a = *(const bf16x8*)(wQ + 65536 + row*256 + ((16*lg + 64*ks) ^ ((row&7)<<4)));
        a2[mf][0] = __builtin_amdgcn_mfma_f32_16x16x32_bf16(a, bt[0][ks], a2[mf][0], 0,0,0);
        a2[mf][1] = __builtin_amdgcn_mfma_f32_16x16x32_bf16(a, bt[1][ks], a2[mf][1], 0,0,0);
      }
    __builtin_amdgcn_s_setprio(0);
    #pragma unroll
    for (int mf = 0; mf < 4; ++mf) {
      const int ch4 = 16*mf + 4*lg;
      const float4 bv = *(const float4*)(qb1 + ch4);
      #pragma unroll
      for (int nf = 0; nf < 2; ++nf) {
        const int node = strip + 16*nf + l15;
        if (node < N) {
          float4 o;
          o.x = tanh_fast(a2[mf][nf][0] + bv.x);
          o.y = tanh_fast(a2[mf][nf][1] + bv.y);
          o.z = tanh_fast(a2[mf][nf][2] + bv.z);
          o.w = tanh_fast(a2[mf][nf][3] + bv.w);
          *(float4*)(out + (size_t)node*64 + ch4) = o;
        }
      }
    }
  }
}

extern "C" void kernel_launch(void* const* d_in, const int* in_sizes, int n_in,
                              void* d_out, int out_size, void* d_ws, size_t ws_size,
                              hipStream_t stream) {
  const float* x   = (const float*)d_in[0];
  const int*   ei  = (const int*)d_in[1];
  const float* ew  = (const float*)d_in[2];
  const float* pw0 = (const float*)d_in[3];
  const float* pb0 = (const float*)d_in[4];
  const float* pw1 = (const float*)d_in[5];
  const float* pb1 = (const float*)d_in[6];
  const float* elw = (const float*)d_in[7];
  const float* elb = (const float*)d_in[8];
  const float* mw0 = (const float*)d_in[9];
  const float* mb0 = (const float*)d_in[10];
  const float* mw1 = (const float*)d_in[11];
  const float* mb1 = (const float*)d_in[12];
  const float* mw2 = (const float*)d_in[13];
  const float* mb2 = (const float*)d_in[14];
  const float* qw0 = (const float*)d_in[15];
  const float* qb0 = (const float*)d_in[16];
  const float* qw1 = (const float*)d_in[17];
  const float* qb1 = (const float*)d_in[18];
  float* out = (float*)d_out;

  const int N = in_sizes[0] / 16;
  const int E = in_sizes[1] / 2;

  char* p = (char*)d_ws;
  auto alloc = [&](size_t bytes) { char* r = p; p += (bytes + 255) & ~(size_t)255; return r; };
  const size_t rowBytes = (size_t)N * 256;

  char* zB      = alloc(rowBytes);           // bf16 [N][128], swizzled content
  char* z3      = alloc(rowBytes);           // bf16 [N][128], swizzled content
  int2* recs    = (int2*)alloc((size_t)E * 8);
  int*  deg     = (int*)alloc((size_t)N * 4);
  int*  offs    = (int*)alloc((size_t)N * 4);
  int*  cur     = (int*)alloc((size_t)N * 4);
  int*  part    = (int*)alloc(256 * 4);
  char* wbf     = alloc(WBF_BYTES);

  char* hB;
  if ((size_t)(p - (char*)d_ws) + rowBytes <= ws_size) {
    hB = alloc(rowBytes);
  } else {
    hB = (char*)d_out;  // alias: each node's h row read before that node's out write
  }

  const int pblk    = (N + 127) / 128;
  const int ntilesA = (N + 223) / 224;
  const int ntilesB = (N + 255) / 256;
  const int nb1  = (N + 2047) / 2048;   // <= 64 for N <= 131072
  const int eblk = (E + 255) / 256;
  const int pgrid = ((13824 > N ? 13824 : N) + 255) / 256;

  wpack_kernel<<<dim3(pgrid), dim3(256), 0, stream>>>(pw0, pw1, mw0, mw1, mw2, qw0, qw1,
                                                      wbf, deg, N);
  prep_kernel<<<dim3(pblk), dim3(256), 0, stream>>>(x, pb0, pb1, wbf, ei, deg, E, hB, N);
  scan_partials_kernel<<<dim3(nb1), dim3(256), 0, stream>>>(deg, part, N);
  scan_apply_kernel<<<dim3(nb1), dim3(256), 0, stream>>>(deg, part, offs, cur, N, nb1);
  scatter_kernel<<<dim3(eblk), dim3(256), 0, stream>>>(ei, ew, cur, recs, E);
  agg_kernel<<<dim3((N + 7) / 8), dim3(256), 0, stream>>>(offs, cur, recs, elw, elb, hB, zB, N);
  nodeA_kernel<<<dim3(256), dim3(448), 0, stream>>>(zB, wbf, mb0, mb1, mb2, z3, N, ntilesA);
  nodeB_kernel<<<dim3(256), dim3(512), 0, stream>>>(z3, hB, wbf, qb0, qb1, out, N, ntilesB);
}